// Round 8
// baseline (783.841 us; speedup 1.0000x reference)
//
#include <hip/hip_runtime.h>
#include <hip/hip_bf16.h>

// FP4 fake-quant MLP via MX-FP4 MFMA (16x16x128, unit block scales).
// This round: A/B two GEMM structures against the r2 baseline (196us each):
//   GEMM1 -> V2: occupancy lane (128x64 block, 64x32 wave tile, acc=32 AGPR,
//               BK=128, dbuf, 24KB LDS, ~5 blocks/CU)
//   GEMM2 -> V1: dbuf-at-equal-occupancy lane (128x128 block, BK=128, dbuf,
//               32KB LDS, ~4 blocks/CU, one barrier per K-tile)
// BK=128 swizzle: LDS slot = chunk ^ ((row>>1)&3); bank quad = 4*(row&1)+slot
// -> uniform 8 lanes/quad on ds_read_b128 (derived, matches r2's 0-conflict
// method). Write side pre-swizzles global source with the same involution.

typedef float f32x4 __attribute__((ext_vector_type(4)));
typedef int   i32x4 __attribute__((ext_vector_type(4)));
typedef int   i32x8 __attribute__((ext_vector_type(8)));

#define AS1 __attribute__((address_space(1)))
#define AS3 __attribute__((address_space(3)))

// ---------- quant helpers ----------
__device__ __forceinline__ float scale_from_amax_bits(unsigned bits) {
    return fmaxf(__uint_as_float(bits) / 6.0f, 1e-12f);
}

// FP4 e2m1 code: idx 0..7 over grid {0,.5,1,1.5,2,3,4,6}, sign in bit 3.
// Compare chain == np.searchsorted(mids, xs, side='left') (ties -> lower mag).
__device__ __forceinline__ unsigned q4(float v, float inv_scale) {
    float xs = fabsf(v) * inv_scale;
    unsigned idx = 0;
    idx += (xs > 0.25f);
    idx += (xs > 0.75f);
    idx += (xs > 1.25f);
    idx += (xs > 1.75f);
    idx += (xs > 2.5f);
    idx += (xs > 3.5f);
    idx += (xs > 5.0f);
    return idx | ((v < 0.0f) ? 8u : 0u);
}

// ---------- tiny utility kernels ----------
__global__ void zero4_kernel(unsigned* p) {
    if (threadIdx.x < 4) p[threadIdx.x] = 0u;
}

__global__ void sentinel_kernel(float* out, long long n) {
    long long i = (long long)blockIdx.x * blockDim.x + threadIdx.x;
    long long stride = (long long)gridDim.x * blockDim.x;
    for (; i < n; i += stride) out[i] = 1e30f;
}

// ---------- fused absmax over the three input tensors (one launch) ----------
__global__ void absmax3_kernel(const float* __restrict__ in0, long long n0,
                               const float* __restrict__ in1, long long n1,
                               const float* __restrict__ in2, long long n2,
                               unsigned* __restrict__ out) {
    const float* in;
    long long n;
    unsigned* o;
    long long nb, b = blockIdx.x;
    if (b < 512)       { in = in0; n = n0; o = out + 0; b -= 0;    nb = 512;  }
    else if (b < 2560) { in = in1; n = n1; o = out + 1; b -= 512;  nb = 2048; }
    else               { in = in2; n = n2; o = out + 3; b -= 2560; nb = 2048; }

    long long i = (b * blockDim.x + threadIdx.x) * 4;
    long long stride = nb * blockDim.x * 4;
    float m = 0.0f;
    for (; i < n; i += stride) {
        float4 v = *(const float4*)&in[i];
        m = fmaxf(m, fmaxf(fmaxf(fabsf(v.x), fabsf(v.y)),
                           fmaxf(fabsf(v.z), fabsf(v.w))));
    }
    #pragma unroll
    for (int off = 32; off > 0; off >>= 1)
        m = fmaxf(m, __shfl_xor(m, off));
    __shared__ float smax[4];
    int lane = threadIdx.x & 63, w = threadIdx.x >> 6;
    if (lane == 0) smax[w] = m;
    __syncthreads();
    if (threadIdx.x == 0) {
        m = fmaxf(fmaxf(smax[0], smax[1]), fmaxf(smax[2], smax[3]));
        atomicMax(o, __float_as_uint(m));  // valid: all values >= 0
    }
}

// ---------- quantize f32 -> packed fp4 (n % 8 == 0), k-major nibbles ----------
__global__ void quant_pack_kernel(const float* __restrict__ in, long long n,
                                  const unsigned* __restrict__ amax,
                                  unsigned* __restrict__ out) {
    float inv = 1.0f / scale_from_amax_bits(*amax);
    long long i = ((long long)blockIdx.x * blockDim.x + threadIdx.x) * 8;
    long long stride = (long long)gridDim.x * blockDim.x * 8;
    for (; i < n; i += stride) {
        float4 a = *(const float4*)&in[i];
        float4 b = *(const float4*)&in[i + 4];
        unsigned u = q4(a.x, inv)        | (q4(a.y, inv) << 4)
                   | (q4(a.z, inv) << 8) | (q4(a.w, inv) << 12)
                   | (q4(b.x, inv) << 16)| (q4(b.y, inv) << 20)
                   | (q4(b.z, inv) << 24)| (q4(b.w, inv) << 28);
        out[i >> 3] = u;
    }
}

// ---------- quantize + transpose + pack: in [R][C] f32 -> out [C][R/2] bytes --
__global__ void quant_transpose_pack_kernel(const float* __restrict__ in, int R, int C,
                                            const unsigned* __restrict__ amax,
                                            unsigned char* __restrict__ out) {
    __shared__ float tile[64][65];
    float inv = 1.0f / scale_from_amax_bits(*amax);
    int t = threadIdx.x;
    int CT = C >> 6;
    int tc = blockIdx.x % CT;
    int tr = blockIdx.x / CT;
    int r0 = t >> 4;            // 0..15
    int c0 = (t & 15) * 4;      // 0..60
    #pragma unroll
    for (int it = 0; it < 4; ++it) {
        int r = r0 + it * 16;
        float4 v = *(const float4*)&in[(size_t)(tr * 64 + r) * C + tc * 64 + c0];
        tile[r][c0 + 0] = v.x;
        tile[r][c0 + 1] = v.y;
        tile[r][c0 + 2] = v.z;
        tile[r][c0 + 3] = v.w;
    }
    __syncthreads();
    int c = t >> 2;             // 0..63 : output row (= input column)
    int rch = (t & 3) * 16;     // k-chunk of 16 values
    unsigned u0 = 0, u1 = 0;
    #pragma unroll
    for (int j = 0; j < 8; ++j) u0 |= q4(tile[rch + j][c], inv) << (4 * j);
    #pragma unroll
    for (int j = 0; j < 8; ++j) u1 |= q4(tile[rch + 8 + j][c], inv) << (4 * j);
    uint2 o; o.x = u0; o.y = u1;
    *(uint2*)&out[(size_t)(tc * 64 + c) * (R >> 1) + (size_t)(tr * 32) + (rch >> 1)] = o;
}

// ---------- fp4 MFMA helper ----------
__device__ __forceinline__ f32x4 mm16(i32x4 a, i32x4 b, f32x4 c) {
    i32x8 a8 = {a[0], a[1], a[2], a[3], 0, 0, 0, 0};
    i32x8 b8 = {b[0], b[1], b[2], b[3], 0, 0, 0, 0};
    return __builtin_amdgcn_mfma_scale_f32_16x16x128_f8f6f4(
        a8, b8, c, 4, 4,            // cbsz=fp4, blgp=fp4
        0, 0x7f7f7f7f,              // scale_a: E8M0 1.0
        0, 0x7f7f7f7f);             // scale_b: E8M0 1.0
}

// ================= V1: 128x128 block, BK=128, dbuf, 32KB LDS =================
template <int RELU, int FUSE_AMAX>
__global__ __launch_bounds__(256, 2)
void gemm_fp4_v1(const unsigned char* __restrict__ Ap,
                 const unsigned char* __restrict__ Bp,
                 float* __restrict__ C, const float* __restrict__ bias,
                 const unsigned* __restrict__ amaxA,
                 const unsigned* __restrict__ amaxB,
                 unsigned* __restrict__ amaxOut,
                 int M, int N, int K) {
    __shared__ alignas(16) unsigned char As[2][128 * 64];  // 16 KB
    __shared__ alignas(16) unsigned char Bs[2][128 * 64];  // 16 KB
    __shared__ float smax[4];

    int nwg = gridDim.x, cpx = nwg >> 3;
    int wg = (blockIdx.x & 7) * cpx + (blockIdx.x >> 3);
    int MT = M >> 7;
    int tm = wg % MT, tn = wg / MT;

    int tid = threadIdx.x, lane = tid & 63, wid = tid >> 6;
    int wr = wid >> 1, wc = wid & 1;    // 2x2 waves, each 64x64

    size_t Kb = (size_t)(K >> 1);

    // staging: thread t fills LDS slot (i_*256 + t): row = i_*64 + (t>>2),
    // slot-chunk t&3 holds global chunk (t&3) ^ ((t>>3)&3)  [(row>>1)&3].
    int csw = ((tid & 3) ^ ((tid >> 3) & 3)) << 4;
    int srow = tid >> 2;                // 0..63
    const unsigned char* Abase = Ap + (size_t)(tm * 128 + srow) * Kb + csw;
    const unsigned char* Bbase = Bp + (size_t)(tn * 128 + srow) * Kb + csw;
    char* AsB = (char*)As;
    char* BsB = (char*)Bs;
    int dstOff = wid << 10;             // + lane*16 by HW

#define STAGE1(d, kt)                                                         \
    do {                                                                      \
        _Pragma("unroll")                                                     \
        for (int i_ = 0; i_ < 2; ++i_) {                                      \
            __builtin_amdgcn_global_load_lds(                                 \
                (const AS1 void*)(Abase + (size_t)(kt) * 64 +                 \
                                  (size_t)(i_ * 64) * Kb),                    \
                (AS3 void*)(AsB + ((d) << 13) + (i_ << 12) + dstOff),         \
                16, 0, 0);                                                    \
            __builtin_amdgcn_global_load_lds(                                 \
                (const AS1 void*)(Bbase + (size_t)(kt) * 64 +                 \
                                  (size_t)(i_ * 64) * Kb),                    \
                (AS3 void*)(BsB + ((d) << 13) + (i_ << 12) + dstOff),         \
                16, 0, 0);                                                    \
        }                                                                     \
    } while (0)

    f32x4 acc[4][4] = {};
    int rrA = wr * 64 + (lane & 15);
    int rrB = wc * 64 + (lane & 15);
    int slotOff = (((lane >> 4) ^ ((lane >> 1) & 3)) << 4);

    int KT = K >> 7;                    // K-tiles of 128 fp4 (64B)

    STAGE1(0, 0);
    __syncthreads();

    for (int t = 0; t < KT; ++t) {
        int d = t & 1;
        if (t + 1 < KT) STAGE1(d ^ 1, t + 1);
        __builtin_amdgcn_sched_barrier(0);

        const char* Aq = AsB + (d << 13);
        const char* Bq = BsB + (d << 13);
        i32x4 a[4], b[4];
        #pragma unroll
        for (int mi = 0; mi < 4; ++mi)
            a[mi] = *(const i32x4*)(Aq + (rrA + mi * 16) * 64 + slotOff);
        #pragma unroll
        for (int ni = 0; ni < 4; ++ni)
            b[ni] = *(const i32x4*)(Bq + (rrB + ni * 16) * 64 + slotOff);
        #pragma unroll
        for (int mi = 0; mi < 4; ++mi)
            #pragma unroll
            for (int ni = 0; ni < 4; ++ni)
                acc[mi][ni] = mm16(a[mi], b[ni], acc[mi][ni]);
        __syncthreads();   // drains vmcnt(0): next buffer staged, reads done
    }
#undef STAGE1

    float s = scale_from_amax_bits(*amaxA) * scale_from_amax_bits(*amaxB);
    float vmax = 0.0f;
    int rowBase = tm * 128 + wr * 64 + (lane >> 4) * 4;
    int colBase = tn * 128 + wc * 64 + (lane & 15);
    #pragma unroll
    for (int mi = 0; mi < 4; ++mi) {
        #pragma unroll
        for (int ni = 0; ni < 4; ++ni) {
            int col = colBase + ni * 16;
            float bv = bias[col];
            int row = rowBase + mi * 16;
            #pragma unroll
            for (int r = 0; r < 4; ++r) {
                float v = acc[mi][ni][r] * s + bv;
                if (RELU) v = fmaxf(v, 0.0f);
                if (FUSE_AMAX) vmax = fmaxf(vmax, fabsf(v));
                C[(size_t)(row + r) * N + col] = v;
            }
        }
    }
    if (FUSE_AMAX) {
        #pragma unroll
        for (int off = 32; off > 0; off >>= 1)
            vmax = fmaxf(vmax, __shfl_xor(vmax, off));
        if (lane == 0) smax[wid] = vmax;
        __syncthreads();
        if (tid == 0) {
            vmax = fmaxf(fmaxf(smax[0], smax[1]), fmaxf(smax[2], smax[3]));
            atomicMax(amaxOut, __float_as_uint(vmax));
        }
    }
}

// ====== V2: 128x64 block, 64x32 wave tile (acc=32 AGPR), BK=128, dbuf =======
template <int RELU, int FUSE_AMAX>
__global__ __launch_bounds__(256, 4)
void gemm_fp4_v2(const unsigned char* __restrict__ Ap,
                 const unsigned char* __restrict__ Bp,
                 float* __restrict__ C, const float* __restrict__ bias,
                 const unsigned* __restrict__ amaxA,
                 const unsigned* __restrict__ amaxB,
                 unsigned* __restrict__ amaxOut,
                 int M, int N, int K) {
    __shared__ alignas(16) unsigned char As[2][128 * 64];  // 16 KB
    __shared__ alignas(16) unsigned char Bs[2][64 * 64];   // 8 KB
    __shared__ float smax[4];

    int nwg = gridDim.x, cpx = nwg >> 3;
    int wg = (blockIdx.x & 7) * cpx + (blockIdx.x >> 3);
    int MT = M >> 7;                    // 128-row tiles
    int tm = wg % MT, tn = wg / MT;     // tn over 64-col tiles

    int tid = threadIdx.x, lane = tid & 63, wid = tid >> 6;
    int wr = wid >> 1, wc = wid & 1;    // wave tile 64(M) x 32(N)

    size_t Kb = (size_t)(K >> 1);

    int csw = ((tid & 3) ^ ((tid >> 3) & 3)) << 4;
    int srow = tid >> 2;                // 0..63
    const unsigned char* Abase = Ap + (size_t)(tm * 128 + srow) * Kb + csw;
    const unsigned char* Bbase = Bp + (size_t)(tn * 64 + srow) * Kb + csw;
    char* AsB = (char*)As;
    char* BsB = (char*)Bs;
    int dstOff = wid << 10;

#define STAGE2(d, kt)                                                         \
    do {                                                                      \
        _Pragma("unroll")                                                     \
        for (int i_ = 0; i_ < 2; ++i_) {                                      \
            __builtin_amdgcn_global_load_lds(                                 \
                (const AS1 void*)(Abase + (size_t)(kt) * 64 +                 \
                                  (size_t)(i_ * 64) * Kb),                    \
                (AS3 void*)(AsB + ((d) << 13) + (i_ << 12) + dstOff),         \
                16, 0, 0);                                                    \
        }                                                                     \
        __builtin_amdgcn_global_load_lds(                                     \
            (const AS1 void*)(Bbase + (size_t)(kt) * 64),                     \
            (AS3 void*)(BsB + ((d) << 12) + dstOff), 16, 0, 0);               \
    } while (0)

    f32x4 acc[4][2] = {};
    int rrA = wr * 64 + (lane & 15);
    int rrB = wc * 32 + (lane & 15);
    int slotOff = (((lane >> 4) ^ ((lane >> 1) & 3)) << 4);

    int KT = K >> 7;

    STAGE2(0, 0);
    __syncthreads();

    for (int t = 0; t < KT; ++t) {
        int d = t & 1;
        if (t + 1 < KT) STAGE2(d ^ 1, t + 1);
        __builtin_amdgcn_sched_barrier(0);

        const char* Aq = AsB + (d << 13);
        const char* Bq = BsB + (d << 12);
        i32x4 a[4], b[2];
        #pragma unroll
        for (int mi = 0; mi < 4; ++mi)
            a[mi] = *(const i32x4*)(Aq + (rrA + mi * 16) * 64 + slotOff);
        #pragma unroll
        for (int ni = 0; ni < 2; ++ni)
            b[ni] = *(const i32x4*)(Bq + (rrB + ni * 16) * 64 + slotOff);
        #pragma unroll
        for (int mi = 0; mi < 4; ++mi)
            #pragma unroll
            for (int ni = 0; ni < 2; ++ni)
                acc[mi][ni] = mm16(a[mi], b[ni], acc[mi][ni]);
        __syncthreads();
    }
#undef STAGE2

    float s = scale_from_amax_bits(*amaxA) * scale_from_amax_bits(*amaxB);
    float vmax = 0.0f;
    int rowBase = tm * 128 + wr * 64 + (lane >> 4) * 4;
    int colBase = tn * 64 + wc * 32 + (lane & 15);
    #pragma unroll
    for (int mi = 0; mi < 4; ++mi) {
        #pragma unroll
        for (int ni = 0; ni < 2; ++ni) {
            int col = colBase + ni * 16;
            float bv = bias[col];
            int row = rowBase + mi * 16;
            #pragma unroll
            for (int r = 0; r < 4; ++r) {
                float v = acc[mi][ni][r] * s + bv;
                if (RELU) v = fmaxf(v, 0.0f);
                if (FUSE_AMAX) vmax = fmaxf(vmax, fabsf(v));
                C[(size_t)(row + r) * N + col] = v;
            }
        }
    }
    if (FUSE_AMAX) {
        #pragma unroll
        for (int off = 32; off > 0; off >>= 1)
            vmax = fmaxf(vmax, __shfl_xor(vmax, off));
        if (lane == 0) smax[wid] = vmax;
        __syncthreads();
        if (tid == 0) {
            vmax = fmaxf(fmaxf(smax[0], smax[1]), fmaxf(smax[2], smax[3]));
            atomicMax(amaxOut, __float_as_uint(vmax));
        }
    }
}

// ---------- launch ----------
extern "C" void kernel_launch(void* const* d_in, const int* in_sizes, int n_in,
                              void* d_out, int out_size, void* d_ws, size_t ws_size,
                              hipStream_t stream) {
    const float* x  = (const float*)d_in[0];
    const float* w1 = (const float*)d_in[1];
    const float* b1 = (const float*)d_in[2];
    const float* w2 = (const float*)d_in[3];
    const float* b2 = (const float*)d_in[4];
    float* out = (float*)d_out;

    const int B = 4096, DIN = 4096, DH = 16384, DOUT = 4096;

    const size_t off_amax = 0;                                    // 4 uints
    const size_t off_Xq   = 256;                                  // 8 MB
    const size_t off_W    = off_Xq + (size_t)B * DIN / 2;         // 32 MB
    const size_t off_h    = off_W + (size_t)DIN * DH / 2;         // 256 MB f32
    const size_t off_Hq   = off_h + (size_t)B * DH * 4;           // 32 MB
    const size_t needed   = off_Hq + (size_t)B * DH / 2;

    if (ws_size < needed) {
        sentinel_kernel<<<2048, 256, 0, stream>>>(out, (long long)out_size);
        return;
    }

    char* ws = (char*)d_ws;
    unsigned* amax = (unsigned*)(ws + off_amax);  // [0]=x [1]=w1 [2]=h [3]=w2
    unsigned char* Xq = (unsigned char*)(ws + off_Xq);
    unsigned char* Wq = (unsigned char*)(ws + off_W);
    float*         h  = (float*)(ws + off_h);
    unsigned char* Hq = (unsigned char*)(ws + off_Hq);

    zero4_kernel<<<1, 64, 0, stream>>>(amax);

    absmax3_kernel<<<4608, 256, 0, stream>>>(x, (long long)B * DIN,
                                             w1, (long long)DIN * DH,
                                             w2, (long long)DH * DOUT, amax);

    quant_pack_kernel<<<2048, 256, 0, stream>>>(x, (long long)B * DIN, amax + 0,
                                                (unsigned*)Xq);
    quant_transpose_pack_kernel<<<(DIN / 64) * (DH / 64), 256, 0, stream>>>(
        w1, DIN, DH, amax + 1, Wq);

    // h = relu(Q(x) @ Q(w1) + b1), fused absmax(h) -> amax[2]   [V2 lane]
    gemm_fp4_v2<1, 1><<<(B / 128) * (DH / 64), 256, 0, stream>>>(
        Xq, Wq, h, b1, amax + 0, amax + 1, amax + 2, B, DH, DIN);

    quant_pack_kernel<<<2048, 256, 0, stream>>>(h, (long long)B * DH, amax + 2,
                                                (unsigned*)Hq);
    quant_transpose_pack_kernel<<<(DH / 64) * (DOUT / 64), 256, 0, stream>>>(
        w2, DH, DOUT, amax + 3, Wq);

    // out = Q(h) @ Q(w2) + b2                                   [V1 lane]
    gemm_fp4_v1<0, 0><<<(B / 128) * (DOUT / 128), 256, 0, stream>>>(
        Hq, Wq, out, b2, amax + 2, amax + 3, nullptr, B, DOUT, DH);
}

// Round 9
// 733.446 us; speedup vs baseline: 1.0687x; 1.0687x over previous
//
#include <hip/hip_runtime.h>
#include <hip/hip_bf16.h>

// FP4 fake-quant MLP via MX-FP4 MFMA (16x16x128, unit block scales).
// Round 9: dbuf with COUNTED vmcnt (T4) — r7/r8's dbuf used __syncthreads,
// whose implicit vmcnt(0) drains the just-issued next-tile loads (exposed
// ~900cy HBM latency per K-iter). Raw s_barrier + s_waitcnt vmcnt(N) waits
// only for the PREVIOUS iter's loads, which had a full compute phase to land.
// A/B: GEMM1 = arm A (BK=256, 64KB LDS, vmcnt(8), 2 blk/CU);
//      GEMM2 = arm B (BK=128, 32KB LDS, vmcnt(4), ~4 blk/CU).
// Baseline to beat: r2 single-buffer = 196us per GEMM.

typedef float f32x4 __attribute__((ext_vector_type(4)));
typedef int   i32x4 __attribute__((ext_vector_type(4)));
typedef int   i32x8 __attribute__((ext_vector_type(8)));

#define AS1 __attribute__((address_space(1)))
#define AS3 __attribute__((address_space(3)))

__device__ __forceinline__ void wg_barrier() {
    asm volatile("" ::: "memory");
    __builtin_amdgcn_s_barrier();
    asm volatile("" ::: "memory");
}

// ---------- quant helpers ----------
__device__ __forceinline__ float scale_from_amax_bits(unsigned bits) {
    return fmaxf(__uint_as_float(bits) / 6.0f, 1e-12f);
}

// FP4 e2m1 code: idx 0..7 over grid {0,.5,1,1.5,2,3,4,6}, sign in bit 3.
// Compare chain == np.searchsorted(mids, xs, side='left') (ties -> lower mag).
__device__ __forceinline__ unsigned q4(float v, float inv_scale) {
    float xs = fabsf(v) * inv_scale;
    unsigned idx = 0;
    idx += (xs > 0.25f);
    idx += (xs > 0.75f);
    idx += (xs > 1.25f);
    idx += (xs > 1.75f);
    idx += (xs > 2.5f);
    idx += (xs > 3.5f);
    idx += (xs > 5.0f);
    return idx | ((v < 0.0f) ? 8u : 0u);
}

// ---------- tiny utility kernels ----------
__global__ void zero4_kernel(unsigned* p) {
    if (threadIdx.x < 4) p[threadIdx.x] = 0u;
}

__global__ void sentinel_kernel(float* out, long long n) {
    long long i = (long long)blockIdx.x * blockDim.x + threadIdx.x;
    long long stride = (long long)gridDim.x * blockDim.x;
    for (; i < n; i += stride) out[i] = 1e30f;
}

// ---------- fused absmax over the three input tensors (one launch) ----------
__global__ void absmax3_kernel(const float* __restrict__ in0, long long n0,
                               const float* __restrict__ in1, long long n1,
                               const float* __restrict__ in2, long long n2,
                               unsigned* __restrict__ out) {
    const float* in;
    long long n;
    unsigned* o;
    long long nb, b = blockIdx.x;
    if (b < 512)       { in = in0; n = n0; o = out + 0; b -= 0;    nb = 512;  }
    else if (b < 2560) { in = in1; n = n1; o = out + 1; b -= 512;  nb = 2048; }
    else               { in = in2; n = n2; o = out + 3; b -= 2560; nb = 2048; }

    long long i = (b * blockDim.x + threadIdx.x) * 4;
    long long stride = nb * blockDim.x * 4;
    float m = 0.0f;
    for (; i < n; i += stride) {
        float4 v = *(const float4*)&in[i];
        m = fmaxf(m, fmaxf(fmaxf(fabsf(v.x), fabsf(v.y)),
                           fmaxf(fabsf(v.z), fabsf(v.w))));
    }
    #pragma unroll
    for (int off = 32; off > 0; off >>= 1)
        m = fmaxf(m, __shfl_xor(m, off));
    __shared__ float smax[4];
    int lane = threadIdx.x & 63, w = threadIdx.x >> 6;
    if (lane == 0) smax[w] = m;
    __syncthreads();
    if (threadIdx.x == 0) {
        m = fmaxf(fmaxf(smax[0], smax[1]), fmaxf(smax[2], smax[3]));
        atomicMax(o, __float_as_uint(m));  // valid: all values >= 0
    }
}

// ---------- quantize f32 -> packed fp4 (n % 8 == 0), k-major nibbles ----------
__global__ void quant_pack_kernel(const float* __restrict__ in, long long n,
                                  const unsigned* __restrict__ amax,
                                  unsigned* __restrict__ out) {
    float inv = 1.0f / scale_from_amax_bits(*amax);
    long long i = ((long long)blockIdx.x * blockDim.x + threadIdx.x) * 8;
    long long stride = (long long)gridDim.x * blockDim.x * 8;
    for (; i < n; i += stride) {
        float4 a = *(const float4*)&in[i];
        float4 b = *(const float4*)&in[i + 4];
        unsigned u = q4(a.x, inv)        | (q4(a.y, inv) << 4)
                   | (q4(a.z, inv) << 8) | (q4(a.w, inv) << 12)
                   | (q4(b.x, inv) << 16)| (q4(b.y, inv) << 20)
                   | (q4(b.z, inv) << 24)| (q4(b.w, inv) << 28);
        out[i >> 3] = u;
    }
}

// ---------- quantize + transpose + pack: in [R][C] f32 -> out [C][R/2] bytes --
__global__ void quant_transpose_pack_kernel(const float* __restrict__ in, int R, int C,
                                            const unsigned* __restrict__ amax,
                                            unsigned char* __restrict__ out) {
    __shared__ float tile[64][65];
    float inv = 1.0f / scale_from_amax_bits(*amax);
    int t = threadIdx.x;
    int CT = C >> 6;
    int tc = blockIdx.x % CT;
    int tr = blockIdx.x / CT;
    int r0 = t >> 4;            // 0..15
    int c0 = (t & 15) * 4;      // 0..60
    #pragma unroll
    for (int it = 0; it < 4; ++it) {
        int r = r0 + it * 16;
        float4 v = *(const float4*)&in[(size_t)(tr * 64 + r) * C + tc * 64 + c0];
        tile[r][c0 + 0] = v.x;
        tile[r][c0 + 1] = v.y;
        tile[r][c0 + 2] = v.z;
        tile[r][c0 + 3] = v.w;
    }
    __syncthreads();
    int c = t >> 2;             // 0..63 : output row (= input column)
    int rch = (t & 3) * 16;     // k-chunk of 16 values
    unsigned u0 = 0, u1 = 0;
    #pragma unroll
    for (int j = 0; j < 8; ++j) u0 |= q4(tile[rch + j][c], inv) << (4 * j);
    #pragma unroll
    for (int j = 0; j < 8; ++j) u1 |= q4(tile[rch + 8 + j][c], inv) << (4 * j);
    uint2 o; o.x = u0; o.y = u1;
    *(uint2*)&out[(size_t)(tc * 64 + c) * (R >> 1) + (size_t)(tr * 32) + (rch >> 1)] = o;
}

// ---------- fp4 MFMA helper ----------
__device__ __forceinline__ f32x4 mm16(i32x4 a, i32x4 b, f32x4 c) {
    i32x8 a8 = {a[0], a[1], a[2], a[3], 0, 0, 0, 0};
    i32x8 b8 = {b[0], b[1], b[2], b[3], 0, 0, 0, 0};
    return __builtin_amdgcn_mfma_scale_f32_16x16x128_f8f6f4(
        a8, b8, c, 4, 4,            // cbsz=fp4, blgp=fp4
        0, 0x7f7f7f7f,              // scale_a: E8M0 1.0
        0, 0x7f7f7f7f);             // scale_b: E8M0 1.0
}

// ========== arm A: 128x128 block, BK=256, dbuf 64KB, counted vmcnt(8) =======
template <int RELU, int FUSE_AMAX>
__global__ __launch_bounds__(256, 2)
void gemm_fp4_a(const unsigned char* __restrict__ Ap,
                const unsigned char* __restrict__ Bp,
                float* __restrict__ C, const float* __restrict__ bias,
                const unsigned* __restrict__ amaxA,
                const unsigned* __restrict__ amaxB,
                unsigned* __restrict__ amaxOut,
                int M, int N, int K) {
    __shared__ alignas(16) unsigned char As[2][128 * 128];  // 32 KB
    __shared__ alignas(16) unsigned char Bs[2][128 * 128];  // 32 KB
    __shared__ float smax[4];

    int nwg = gridDim.x, cpx = nwg >> 3;
    int wg = (blockIdx.x & 7) * cpx + (blockIdx.x >> 3);
    int MT = M >> 7;
    int tm = wg % MT, tn = wg / MT;

    int tid = threadIdx.x, lane = tid & 63, wid = tid >> 6;
    int wr = wid >> 1, wc = wid & 1;    // 2x2 waves, each owns 64x64

    size_t Kb = (size_t)(K >> 1);

    // staging (r2-proven): lane covers row wid*32 + (lane>>3), chunk lane&7;
    // global source chunk pre-swizzled with slot = chunk ^ (row&7).
    int cs = ((lane & 7) ^ ((lane >> 3) & 7)) << 4;
    int srow = wid * 32 + (lane >> 3);
    const unsigned char* Abase = Ap + (size_t)(tm * 128 + srow) * Kb + cs;
    const unsigned char* Bbase = Bp + (size_t)(tn * 128 + srow) * Kb + cs;
    char* AsB = (char*)As;
    char* BsB = (char*)Bs;
    int ldsOff = wid * 4096;

#define STAGE_A(d, kt)                                                        \
    do {                                                                      \
        _Pragma("unroll")                                                     \
        for (int i_ = 0; i_ < 4; ++i_) {                                      \
            __builtin_amdgcn_global_load_lds(                                 \
                (const AS1 void*)(Abase + (size_t)(kt) * 128 +                \
                                  (size_t)(i_ * 8) * Kb),                     \
                (AS3 void*)(AsB + ((d) << 14) + ldsOff + i_ * 1024),          \
                16, 0, 0);                                                    \
            __builtin_amdgcn_global_load_lds(                                 \
                (const AS1 void*)(Bbase + (size_t)(kt) * 128 +                \
                                  (size_t)(i_ * 8) * Kb),                     \
                (AS3 void*)(BsB + ((d) << 14) + ldsOff + i_ * 1024),          \
                16, 0, 0);                                                    \
        }                                                                     \
    } while (0)

    f32x4 acc[4][4] = {};
    int rrA = wr * 64 + (lane & 15);
    int rrB = wc * 64 + (lane & 15);

    int KT = K >> 8;                    // K-tiles of 256 fp4 (128B)

    STAGE_A(0, 0);                      // 8 outstanding

    for (int t = 0; t < KT; ++t) {
        int d = t & 1;
        // issue next tile, then wait ONLY for current tile's loads (T4):
        if (t + 1 < KT) {
            STAGE_A(d ^ 1, t + 1);
            __builtin_amdgcn_sched_barrier(0);
            asm volatile("s_waitcnt vmcnt(8)" ::: "memory");
        } else {
            asm volatile("s_waitcnt vmcnt(0)" ::: "memory");
        }
        wg_barrier();                   // buf d complete for ALL waves

        const char* Aq = AsB + (d << 14);
        const char* Bq = BsB + (d << 14);
        #pragma unroll
        for (int ks = 0; ks < 2; ++ks) {
            int slotOff = ((ks * 4 + (lane >> 4)) ^ (lane & 7)) << 4;
            i32x4 a[4], b[4];
            #pragma unroll
            for (int mi = 0; mi < 4; ++mi)
                a[mi] = *(const i32x4*)(Aq + (rrA + mi * 16) * 128 + slotOff);
            #pragma unroll
            for (int ni = 0; ni < 4; ++ni)
                b[ni] = *(const i32x4*)(Bq + (rrB + ni * 16) * 128 + slotOff);
            #pragma unroll
            for (int mi = 0; mi < 4; ++mi)
                #pragma unroll
                for (int ni = 0; ni < 4; ++ni)
                    acc[mi][ni] = mm16(a[mi], b[ni], acc[mi][ni]);
        }
        asm volatile("s_waitcnt lgkmcnt(0)" ::: "memory");
        wg_barrier();                   // all waves done reading buf d
    }
#undef STAGE_A

    float s = scale_from_amax_bits(*amaxA) * scale_from_amax_bits(*amaxB);
    float vmax = 0.0f;
    int rowBase = tm * 128 + wr * 64 + (lane >> 4) * 4;
    int colBase = tn * 128 + wc * 64 + (lane & 15);
    #pragma unroll
    for (int mi = 0; mi < 4; ++mi) {
        #pragma unroll
        for (int ni = 0; ni < 4; ++ni) {
            int col = colBase + ni * 16;
            float bv = bias[col];
            int row = rowBase + mi * 16;
            #pragma unroll
            for (int r = 0; r < 4; ++r) {
                float v = acc[mi][ni][r] * s + bv;
                if (RELU) v = fmaxf(v, 0.0f);
                if (FUSE_AMAX) vmax = fmaxf(vmax, fabsf(v));
                C[(size_t)(row + r) * N + col] = v;
            }
        }
    }
    if (FUSE_AMAX) {
        #pragma unroll
        for (int off = 32; off > 0; off >>= 1)
            vmax = fmaxf(vmax, __shfl_xor(vmax, off));
        if (lane == 0) smax[wid] = vmax;
        __syncthreads();
        if (tid == 0) {
            vmax = fmaxf(fmaxf(smax[0], smax[1]), fmaxf(smax[2], smax[3]));
            atomicMax(amaxOut, __float_as_uint(vmax));
        }
    }
}

// ========== arm B: 128x128 block, BK=128, dbuf 32KB, counted vmcnt(4) =======
template <int RELU, int FUSE_AMAX>
__global__ __launch_bounds__(256, 4)
void gemm_fp4_b(const unsigned char* __restrict__ Ap,
                const unsigned char* __restrict__ Bp,
                float* __restrict__ C, const float* __restrict__ bias,
                const unsigned* __restrict__ amaxA,
                const unsigned* __restrict__ amaxB,
                unsigned* __restrict__ amaxOut,
                int M, int N, int K) {
    __shared__ alignas(16) unsigned char As[2][128 * 64];  // 16 KB
    __shared__ alignas(16) unsigned char Bs[2][128 * 64];  // 16 KB
    __shared__ float smax[4];

    int nwg = gridDim.x, cpx = nwg >> 3;
    int wg = (blockIdx.x & 7) * cpx + (blockIdx.x >> 3);
    int MT = M >> 7;
    int tm = wg % MT, tn = wg / MT;

    int tid = threadIdx.x, lane = tid & 63, wid = tid >> 6;
    int wr = wid >> 1, wc = wid & 1;

    size_t Kb = (size_t)(K >> 1);

    // BK=128 swizzle: LDS slot = chunk ^ ((row>>1)&3). Stage: thread t covers
    // row i_*64 + (t>>2), slot-chunk t&3 <- global chunk (t&3)^((t>>3)&3).
    int csw = ((tid & 3) ^ ((tid >> 3) & 3)) << 4;
    int srow = tid >> 2;                // 0..63
    const unsigned char* Abase = Ap + (size_t)(tm * 128 + srow) * Kb + csw;
    const unsigned char* Bbase = Bp + (size_t)(tn * 128 + srow) * Kb + csw;
    char* AsB = (char*)As;
    char* BsB = (char*)Bs;
    int dstOff = wid << 10;

#define STAGE_B(d, kt)                                                        \
    do {                                                                      \
        _Pragma("unroll")                                                     \
        for (int i_ = 0; i_ < 2; ++i_) {                                      \
            __builtin_amdgcn_global_load_lds(                                 \
                (const AS1 void*)(Abase + (size_t)(kt) * 64 +                 \
                                  (size_t)(i_ * 64) * Kb),                    \
                (AS3 void*)(AsB + ((d) << 13) + (i_ << 12) + dstOff),         \
                16, 0, 0);                                                    \
            __builtin_amdgcn_global_load_lds(                                 \
                (const AS1 void*)(Bbase + (size_t)(kt) * 64 +                 \
                                  (size_t)(i_ * 64) * Kb),                    \
                (AS3 void*)(BsB + ((d) << 13) + (i_ << 12) + dstOff),         \
                16, 0, 0);                                                    \
        }                                                                     \
    } while (0)

    f32x4 acc[4][4] = {};
    int rrA = wr * 64 + (lane & 15);
    int rrB = wc * 64 + (lane & 15);
    int slotOff = (((lane >> 4) ^ ((lane >> 1) & 3)) << 4);

    int KT = K >> 7;                    // K-tiles of 128 fp4 (64B)

    STAGE_B(0, 0);                      // 4 outstanding

    for (int t = 0; t < KT; ++t) {
        int d = t & 1;
        if (t + 1 < KT) {
            STAGE_B(d ^ 1, t + 1);
            __builtin_amdgcn_sched_barrier(0);
            asm volatile("s_waitcnt vmcnt(4)" ::: "memory");
        } else {
            asm volatile("s_waitcnt vmcnt(0)" ::: "memory");
        }
        wg_barrier();

        const char* Aq = AsB + (d << 13);
        const char* Bq = BsB + (d << 13);
        i32x4 a[4], b[4];
        #pragma unroll
        for (int mi = 0; mi < 4; ++mi)
            a[mi] = *(const i32x4*)(Aq + (rrA + mi * 16) * 64 + slotOff);
        #pragma unroll
        for (int ni = 0; ni < 4; ++ni)
            b[ni] = *(const i32x4*)(Bq + (rrB + ni * 16) * 64 + slotOff);
        #pragma unroll
        for (int mi = 0; mi < 4; ++mi)
            #pragma unroll
            for (int ni = 0; ni < 4; ++ni)
                acc[mi][ni] = mm16(a[mi], b[ni], acc[mi][ni]);

        asm volatile("s_waitcnt lgkmcnt(0)" ::: "memory");
        wg_barrier();
    }
#undef STAGE_B

    float s = scale_from_amax_bits(*amaxA) * scale_from_amax_bits(*amaxB);
    float vmax = 0.0f;
    int rowBase = tm * 128 + wr * 64 + (lane >> 4) * 4;
    int colBase = tn * 128 + wc * 64 + (lane & 15);
    #pragma unroll
    for (int mi = 0; mi < 4; ++mi) {
        #pragma unroll
        for (int ni = 0; ni < 4; ++ni) {
            int col = colBase + ni * 16;
            float bv = bias[col];
            int row = rowBase + mi * 16;
            #pragma unroll
            for (int r = 0; r < 4; ++r) {
                float v = acc[mi][ni][r] * s + bv;
                if (RELU) v = fmaxf(v, 0.0f);
                if (FUSE_AMAX) vmax = fmaxf(vmax, fabsf(v));
                C[(size_t)(row + r) * N + col] = v;
            }
        }
    }
    if (FUSE_AMAX) {
        #pragma unroll
        for (int off = 32; off > 0; off >>= 1)
            vmax = fmaxf(vmax, __shfl_xor(vmax, off));
        if (lane == 0) smax[wid] = vmax;
        __syncthreads();
        if (tid == 0) {
            vmax = fmaxf(fmaxf(smax[0], smax[1]), fmaxf(smax[2], smax[3]));
            atomicMax(amaxOut, __float_as_uint(vmax));
        }
    }
}

// ---------- launch ----------
extern "C" void kernel_launch(void* const* d_in, const int* in_sizes, int n_in,
                              void* d_out, int out_size, void* d_ws, size_t ws_size,
                              hipStream_t stream) {
    const float* x  = (const float*)d_in[0];
    const float* w1 = (const float*)d_in[1];
    const float* b1 = (const float*)d_in[2];
    const float* w2 = (const float*)d_in[3];
    const float* b2 = (const float*)d_in[4];
    float* out = (float*)d_out;

    const int B = 4096, DIN = 4096, DH = 16384, DOUT = 4096;

    const size_t off_amax = 0;                                    // 4 uints
    const size_t off_Xq   = 256;                                  // 8 MB
    const size_t off_W    = off_Xq + (size_t)B * DIN / 2;         // 32 MB
    const size_t off_h    = off_W + (size_t)DIN * DH / 2;         // 256 MB f32
    const size_t off_Hq   = off_h + (size_t)B * DH * 4;           // 32 MB
    const size_t needed   = off_Hq + (size_t)B * DH / 2;

    if (ws_size < needed) {
        sentinel_kernel<<<2048, 256, 0, stream>>>(out, (long long)out_size);
        return;
    }

    char* ws = (char*)d_ws;
    unsigned* amax = (unsigned*)(ws + off_amax);  // [0]=x [1]=w1 [2]=h [3]=w2
    unsigned char* Xq = (unsigned char*)(ws + off_Xq);
    unsigned char* Wq = (unsigned char*)(ws + off_W);
    float*         h  = (float*)(ws + off_h);
    unsigned char* Hq = (unsigned char*)(ws + off_Hq);

    zero4_kernel<<<1, 64, 0, stream>>>(amax);

    absmax3_kernel<<<4608, 256, 0, stream>>>(x, (long long)B * DIN,
                                             w1, (long long)DIN * DH,
                                             w2, (long long)DH * DOUT, amax);

    quant_pack_kernel<<<2048, 256, 0, stream>>>(x, (long long)B * DIN, amax + 0,
                                                (unsigned*)Xq);
    quant_transpose_pack_kernel<<<(DIN / 64) * (DH / 64), 256, 0, stream>>>(
        w1, DIN, DH, amax + 1, Wq);

    // h = relu(Q(x) @ Q(w1) + b1), fused absmax(h) -> amax[2]   [arm A]
    gemm_fp4_a<1, 1><<<(B / 128) * (DH / 128), 256, 0, stream>>>(
        Xq, Wq, h, b1, amax + 0, amax + 1, amax + 2, B, DH, DIN);

    quant_pack_kernel<<<2048, 256, 0, stream>>>(h, (long long)B * DH, amax + 2,
                                                (unsigned*)Hq);
    quant_transpose_pack_kernel<<<(DH / 64) * (DOUT / 64), 256, 0, stream>>>(
        w2, DH, DOUT, amax + 3, Wq);

    // out = Q(h) @ Q(w2) + b2                                   [arm B]
    gemm_fp4_b<0, 0><<<(B / 128) * (DOUT / 128), 256, 0, stream>>>(
        Hq, Wq, out, b2, amax + 2, amax + 3, nullptr, B, DOUT, DH);
}

// Round 10
// 710.265 us; speedup vs baseline: 1.1036x; 1.0326x over previous
//
#include <hip/hip_runtime.h>
#include <hip/hip_bf16.h>

// FP4 fake-quant MLP via MX-FP4 MFMA.
// Winning structure (r8-V1 / r9-armB residuals): 128x128 block, BK=128,
// double-buffered 32KB LDS, 4 blocks/CU, one __syncthreads per K-tile.
// This round A/Bs the MFMA shape at that structure:
//   GEMM1 = 16x16x128 (known-good, ~169us)   GEMM2 = 32x32x64 (9.1 vs 7.2 PF)

typedef float f32x4  __attribute__((ext_vector_type(4)));
typedef float f32x16 __attribute__((ext_vector_type(16)));
typedef int   i32x4  __attribute__((ext_vector_type(4)));
typedef int   i32x8  __attribute__((ext_vector_type(8)));

#define AS1 __attribute__((address_space(1)))
#define AS3 __attribute__((address_space(3)))

// ---------- quant helpers ----------
__device__ __forceinline__ float scale_from_amax_bits(unsigned bits) {
    return fmaxf(__uint_as_float(bits) / 6.0f, 1e-12f);
}

// FP4 e2m1 code: idx 0..7 over grid {0,.5,1,1.5,2,3,4,6}, sign in bit 3.
// Compare chain == np.searchsorted(mids, xs, side='left') (ties -> lower mag).
__device__ __forceinline__ unsigned q4(float v, float inv_scale) {
    float xs = fabsf(v) * inv_scale;
    unsigned idx = 0;
    idx += (xs > 0.25f);
    idx += (xs > 0.75f);
    idx += (xs > 1.25f);
    idx += (xs > 1.75f);
    idx += (xs > 2.5f);
    idx += (xs > 3.5f);
    idx += (xs > 5.0f);
    return idx | ((v < 0.0f) ? 8u : 0u);
}

// ---------- tiny utility kernels ----------
__global__ void zero4_kernel(unsigned* p) {
    if (threadIdx.x < 4) p[threadIdx.x] = 0u;
}

__global__ void sentinel_kernel(float* out, long long n) {
    long long i = (long long)blockIdx.x * blockDim.x + threadIdx.x;
    long long stride = (long long)gridDim.x * blockDim.x;
    for (; i < n; i += stride) out[i] = 1e30f;
}

// ---------- fused absmax over the three input tensors (one launch) ----------
__global__ void absmax3_kernel(const float* __restrict__ in0, long long n0,
                               const float* __restrict__ in1, long long n1,
                               const float* __restrict__ in2, long long n2,
                               unsigned* __restrict__ out) {
    const float* in;
    long long n;
    unsigned* o;
    long long nb, b = blockIdx.x;
    if (b < 512)       { in = in0; n = n0; o = out + 0; b -= 0;    nb = 512;  }
    else if (b < 2560) { in = in1; n = n1; o = out + 1; b -= 512;  nb = 2048; }
    else               { in = in2; n = n2; o = out + 3; b -= 2560; nb = 2048; }

    long long i = (b * blockDim.x + threadIdx.x) * 4;
    long long stride = nb * blockDim.x * 4;
    float m = 0.0f;
    for (; i < n; i += stride) {
        float4 v = *(const float4*)&in[i];
        m = fmaxf(m, fmaxf(fmaxf(fabsf(v.x), fabsf(v.y)),
                           fmaxf(fabsf(v.z), fabsf(v.w))));
    }
    #pragma unroll
    for (int off = 32; off > 0; off >>= 1)
        m = fmaxf(m, __shfl_xor(m, off));
    __shared__ float smax[4];
    int lane = threadIdx.x & 63, w = threadIdx.x >> 6;
    if (lane == 0) smax[w] = m;
    __syncthreads();
    if (threadIdx.x == 0) {
        m = fmaxf(fmaxf(smax[0], smax[1]), fmaxf(smax[2], smax[3]));
        atomicMax(o, __float_as_uint(m));  // valid: all values >= 0
    }
}

// ---------- quantize f32 -> packed fp4 (n % 8 == 0), k-major nibbles ----------
__global__ void quant_pack_kernel(const float* __restrict__ in, long long n,
                                  const unsigned* __restrict__ amax,
                                  unsigned* __restrict__ out) {
    float inv = 1.0f / scale_from_amax_bits(*amax);
    long long i = ((long long)blockIdx.x * blockDim.x + threadIdx.x) * 8;
    long long stride = (long long)gridDim.x * blockDim.x * 8;
    for (; i < n; i += stride) {
        float4 a = *(const float4*)&in[i];
        float4 b = *(const float4*)&in[i + 4];
        unsigned u = q4(a.x, inv)        | (q4(a.y, inv) << 4)
                   | (q4(a.z, inv) << 8) | (q4(a.w, inv) << 12)
                   | (q4(b.x, inv) << 16)| (q4(b.y, inv) << 20)
                   | (q4(b.z, inv) << 24)| (q4(b.w, inv) << 28);
        out[i >> 3] = u;
    }
}

// ---------- quantize + transpose + pack: in [R][C] f32 -> out [C][R/2] bytes --
__global__ void quant_transpose_pack_kernel(const float* __restrict__ in, int R, int C,
                                            const unsigned* __restrict__ amax,
                                            unsigned char* __restrict__ out) {
    __shared__ float tile[64][65];
    float inv = 1.0f / scale_from_amax_bits(*amax);
    int t = threadIdx.x;
    int CT = C >> 6;
    int tc = blockIdx.x % CT;
    int tr = blockIdx.x / CT;
    int r0 = t >> 4;            // 0..15
    int c0 = (t & 15) * 4;      // 0..60
    #pragma unroll
    for (int it = 0; it < 4; ++it) {
        int r = r0 + it * 16;
        float4 v = *(const float4*)&in[(size_t)(tr * 64 + r) * C + tc * 64 + c0];
        tile[r][c0 + 0] = v.x;
        tile[r][c0 + 1] = v.y;
        tile[r][c0 + 2] = v.z;
        tile[r][c0 + 3] = v.w;
    }
    __syncthreads();
    int c = t >> 2;             // 0..63 : output row (= input column)
    int rch = (t & 3) * 16;     // k-chunk of 16 values
    unsigned u0 = 0, u1 = 0;
    #pragma unroll
    for (int j = 0; j < 8; ++j) u0 |= q4(tile[rch + j][c], inv) << (4 * j);
    #pragma unroll
    for (int j = 0; j < 8; ++j) u1 |= q4(tile[rch + 8 + j][c], inv) << (4 * j);
    uint2 o; o.x = u0; o.y = u1;
    *(uint2*)&out[(size_t)(tc * 64 + c) * (R >> 1) + (size_t)(tr * 32) + (rch >> 1)] = o;
}

// ---------- fp4 MFMA helpers ----------
__device__ __forceinline__ f32x4 mm16(i32x4 a, i32x4 b, f32x4 c) {
    i32x8 a8 = {a[0], a[1], a[2], a[3], 0, 0, 0, 0};
    i32x8 b8 = {b[0], b[1], b[2], b[3], 0, 0, 0, 0};
    return __builtin_amdgcn_mfma_scale_f32_16x16x128_f8f6f4(
        a8, b8, c, 4, 4, 0, 0x7f7f7f7f, 0, 0x7f7f7f7f);
}
__device__ __forceinline__ f32x16 mm32(i32x4 a, i32x4 b, f32x16 c) {
    i32x8 a8 = {a[0], a[1], a[2], a[3], 0, 0, 0, 0};
    i32x8 b8 = {b[0], b[1], b[2], b[3], 0, 0, 0, 0};
    return __builtin_amdgcn_mfma_scale_f32_32x32x64_f8f6f4(
        a8, b8, c, 4, 4, 0, 0x7f7f7f7f, 0, 0x7f7f7f7f);
}

// Common geometry for both GEMMs: 128x128 block, BK=128 (64B rows), dbuf.
// Staging: thread t covers row i_*64 + (t>>2), LDS slot t&3 holds global
// chunk (t&3) ^ ((row>>1)&3) = (t&3) ^ ((t>>3)&3)  [pre-swizzled source];
// read side applies the same XOR (involution, rule #21). 0 conflicts (r8).
#define GEMM_PROLOG(AP, BP)                                                   \
    int nwg = gridDim.x, cpx = nwg >> 3;                                      \
    int wg = (blockIdx.x & 7) * cpx + (blockIdx.x >> 3);                      \
    int MT = M >> 7;                                                          \
    int tm = wg % MT, tn = wg / MT;                                           \
    int tid = threadIdx.x, lane = tid & 63, wid = tid >> 6;                   \
    int wr = wid >> 1, wc = wid & 1;                                          \
    size_t Kb = (size_t)(K >> 1);                                             \
    int csw = ((tid & 3) ^ ((tid >> 3) & 3)) << 4;                            \
    int srow = tid >> 2;                                                      \
    const unsigned char* Abase = (AP) + (size_t)(tm * 128 + srow) * Kb + csw; \
    const unsigned char* Bbase = (BP) + (size_t)(tn * 128 + srow) * Kb + csw; \
    char* AsB = (char*)As;                                                    \
    char* BsB = (char*)Bs;                                                    \
    int dstOff = wid << 10;

#define STAGE(d, kt)                                                          \
    do {                                                                      \
        _Pragma("unroll")                                                     \
        for (int i_ = 0; i_ < 2; ++i_) {                                      \
            __builtin_amdgcn_global_load_lds(                                 \
                (const AS1 void*)(Abase + (size_t)(kt) * 64 +                 \
                                  (size_t)(i_ * 64) * Kb),                    \
                (AS3 void*)(AsB + ((d) << 13) + (i_ << 12) + dstOff),         \
                16, 0, 0);                                                    \
            __builtin_amdgcn_global_load_lds(                                 \
                (const AS1 void*)(Bbase + (size_t)(kt) * 64 +                 \
                                  (size_t)(i_ * 64) * Kb),                    \
                (AS3 void*)(BsB + ((d) << 13) + (i_ << 12) + dstOff),         \
                16, 0, 0);                                                    \
        }                                                                     \
    } while (0)

#define AMAX_EPILOG                                                           \
    if (FUSE_AMAX) {                                                          \
        _Pragma("unroll")                                                     \
        for (int off = 32; off > 0; off >>= 1)                                \
            vmax = fmaxf(vmax, __shfl_xor(vmax, off));                        \
        if (lane == 0) smax[wid] = vmax;                                      \
        __syncthreads();                                                      \
        if (tid == 0) {                                                       \
            vmax = fmaxf(fmaxf(smax[0], smax[1]), fmaxf(smax[2], smax[3]));   \
            atomicMax(amaxOut, __float_as_uint(vmax));                        \
        }                                                                     \
    }

// ========== s16: 16x16x128 MFMA (r8-V1 proven, ~169us) ==========
template <int RELU, int FUSE_AMAX>
__global__ __launch_bounds__(256, 4)
void gemm_fp4_s16(const unsigned char* __restrict__ Ap,
                  const unsigned char* __restrict__ Bp,
                  float* __restrict__ C, const float* __restrict__ bias,
                  const unsigned* __restrict__ amaxA,
                  const unsigned* __restrict__ amaxB,
                  unsigned* __restrict__ amaxOut,
                  int M, int N, int K) {
    __shared__ alignas(16) unsigned char As[2][128 * 64];  // 16 KB
    __shared__ alignas(16) unsigned char Bs[2][128 * 64];  // 16 KB
    __shared__ float smax[4];
    GEMM_PROLOG(Ap, Bp)

    f32x4 acc[4][4] = {};
    int rrA = wr * 64 + (lane & 15);
    int rrB = wc * 64 + (lane & 15);
    int slotOff = (((lane >> 4) ^ ((lane >> 1) & 3)) << 4);

    int KT = K >> 7;
    STAGE(0, 0);
    __syncthreads();

    for (int t = 0; t < KT; ++t) {
        int d = t & 1;
        if (t + 1 < KT) STAGE(d ^ 1, t + 1);
        __builtin_amdgcn_sched_barrier(0);

        const char* Aq = AsB + (d << 13);
        const char* Bq = BsB + (d << 13);
        i32x4 a[4], b[4];
        #pragma unroll
        for (int mi = 0; mi < 4; ++mi)
            a[mi] = *(const i32x4*)(Aq + (rrA + mi * 16) * 64 + slotOff);
        #pragma unroll
        for (int ni = 0; ni < 4; ++ni)
            b[ni] = *(const i32x4*)(Bq + (rrB + ni * 16) * 64 + slotOff);
        #pragma unroll
        for (int mi = 0; mi < 4; ++mi)
            #pragma unroll
            for (int ni = 0; ni < 4; ++ni)
                acc[mi][ni] = mm16(a[mi], b[ni], acc[mi][ni]);
        __syncthreads();
    }

    float s = scale_from_amax_bits(*amaxA) * scale_from_amax_bits(*amaxB);
    float vmax = 0.0f;
    int rowBase = tm * 128 + wr * 64 + (lane >> 4) * 4;
    int colBase = tn * 128 + wc * 64 + (lane & 15);
    #pragma unroll
    for (int mi = 0; mi < 4; ++mi) {
        #pragma unroll
        for (int ni = 0; ni < 4; ++ni) {
            int col = colBase + ni * 16;
            float bv = bias[col];
            int row = rowBase + mi * 16;
            #pragma unroll
            for (int r = 0; r < 4; ++r) {
                float v = acc[mi][ni][r] * s + bv;
                if (RELU) v = fmaxf(v, 0.0f);
                if (FUSE_AMAX) vmax = fmaxf(vmax, fabsf(v));
                C[(size_t)(row + r) * N + col] = v;
            }
        }
    }
    AMAX_EPILOG
}

// ========== s32: 32x32x64 MFMA (9.1 PF ceiling; layout verified in r6) ======
// A-frag: row = (wave 64-half) + mi*32 + (lane&31); 16B chunk = ks*2+(lane>>5).
// C/D: col = lane&31 (+ni*32), row = 4*(lane>>5) + rg*8 + rr (+mi*32).
template <int RELU, int FUSE_AMAX>
__global__ __launch_bounds__(256, 4)
void gemm_fp4_s32(const unsigned char* __restrict__ Ap,
                  const unsigned char* __restrict__ Bp,
                  float* __restrict__ C, const float* __restrict__ bias,
                  const unsigned* __restrict__ amaxA,
                  const unsigned* __restrict__ amaxB,
                  unsigned* __restrict__ amaxOut,
                  int M, int N, int K) {
    __shared__ alignas(16) unsigned char As[2][128 * 64];  // 16 KB
    __shared__ alignas(16) unsigned char Bs[2][128 * 64];  // 16 KB
    __shared__ float smax[4];
    GEMM_PROLOG(Ap, Bp)

    f32x16 acc[2][2] = {};
    int rrA = wr * 64 + (lane & 31);
    int rrB = wc * 64 + (lane & 31);
    int kh = lane >> 5;
    int so[2];
    #pragma unroll
    for (int ks = 0; ks < 2; ++ks)
        so[ks] = (((ks * 2 + kh) ^ ((lane >> 1) & 3)) << 4);

    int KT = K >> 7;
    STAGE(0, 0);
    __syncthreads();

    for (int t = 0; t < KT; ++t) {
        int d = t & 1;
        if (t + 1 < KT) STAGE(d ^ 1, t + 1);
        __builtin_amdgcn_sched_barrier(0);

        const char* Aq = AsB + (d << 13);
        const char* Bq = BsB + (d << 13);
        i32x4 a[2][2], b[2][2];
        #pragma unroll
        for (int mi = 0; mi < 2; ++mi)
            #pragma unroll
            for (int ks = 0; ks < 2; ++ks)
                a[mi][ks] = *(const i32x4*)(Aq + (rrA + mi * 32) * 64 + so[ks]);
        #pragma unroll
        for (int ni = 0; ni < 2; ++ni)
            #pragma unroll
            for (int ks = 0; ks < 2; ++ks)
                b[ni][ks] = *(const i32x4*)(Bq + (rrB + ni * 32) * 64 + so[ks]);
        #pragma unroll
        for (int mi = 0; mi < 2; ++mi)
            #pragma unroll
            for (int ni = 0; ni < 2; ++ni)
                #pragma unroll
                for (int ks = 0; ks < 2; ++ks)
                    acc[mi][ni] = mm32(a[mi][ks], b[ni][ks], acc[mi][ni]);
        __syncthreads();
    }

    float s = scale_from_amax_bits(*amaxA) * scale_from_amax_bits(*amaxB);
    float vmax = 0.0f;
    int rowBase = tm * 128 + wr * 64 + kh * 4;
    int colBase = tn * 128 + wc * 64 + (lane & 31);
    #pragma unroll
    for (int mi = 0; mi < 2; ++mi) {
        #pragma unroll
        for (int ni = 0; ni < 2; ++ni) {
            int col = colBase + ni * 32;
            float bv = bias[col];
            #pragma unroll
            for (int rg = 0; rg < 4; ++rg) {
                #pragma unroll
                for (int rr = 0; rr < 4; ++rr) {
                    float v = acc[mi][ni][rg * 4 + rr] * s + bv;
                    if (RELU) v = fmaxf(v, 0.0f);
                    if (FUSE_AMAX) vmax = fmaxf(vmax, fabsf(v));
                    C[(size_t)(rowBase + mi * 32 + rg * 8 + rr) * N + col] = v;
                }
            }
        }
    }
    AMAX_EPILOG
}

// ---------- launch ----------
extern "C" void kernel_launch(void* const* d_in, const int* in_sizes, int n_in,
                              void* d_out, int out_size, void* d_ws, size_t ws_size,
                              hipStream_t stream) {
    const float* x  = (const float*)d_in[0];
    const float* w1 = (const float*)d_in[1];
    const float* b1 = (const float*)d_in[2];
    const float* w2 = (const float*)d_in[3];
    const float* b2 = (const float*)d_in[4];
    float* out = (float*)d_out;

    const int B = 4096, DIN = 4096, DH = 16384, DOUT = 4096;

    const size_t off_amax = 0;                                    // 4 uints
    const size_t off_Xq   = 256;                                  // 8 MB
    const size_t off_W    = off_Xq + (size_t)B * DIN / 2;         // 32 MB
    const size_t off_h    = off_W + (size_t)DIN * DH / 2;         // 256 MB f32
    const size_t off_Hq   = off_h + (size_t)B * DH * 4;           // 32 MB
    const size_t needed   = off_Hq + (size_t)B * DH / 2;

    if (ws_size < needed) {
        sentinel_kernel<<<2048, 256, 0, stream>>>(out, (long long)out_size);
        return;
    }

    char* ws = (char*)d_ws;
    unsigned* amax = (unsigned*)(ws + off_amax);  // [0]=x [1]=w1 [2]=h [3]=w2
    unsigned char* Xq = (unsigned char*)(ws + off_Xq);
    unsigned char* Wq = (unsigned char*)(ws + off_W);
    float*         h  = (float*)(ws + off_h);
    unsigned char* Hq = (unsigned char*)(ws + off_Hq);

    zero4_kernel<<<1, 64, 0, stream>>>(amax);

    absmax3_kernel<<<4608, 256, 0, stream>>>(x, (long long)B * DIN,
                                             w1, (long long)DIN * DH,
                                             w2, (long long)DH * DOUT, amax);

    quant_pack_kernel<<<2048, 256, 0, stream>>>(x, (long long)B * DIN, amax + 0,
                                                (unsigned*)Xq);
    quant_transpose_pack_kernel<<<(DIN / 64) * (DH / 64), 256, 0, stream>>>(
        w1, DIN, DH, amax + 1, Wq);

    // h = relu(Q(x) @ Q(w1) + b1), fused absmax(h) -> amax[2]   [16x16 arm]
    gemm_fp4_s16<1, 1><<<(B / 128) * (DH / 128), 256, 0, stream>>>(
        Xq, Wq, h, b1, amax + 0, amax + 1, amax + 2, B, DH, DIN);

    quant_pack_kernel<<<2048, 256, 0, stream>>>(h, (long long)B * DH, amax + 2,
                                                (unsigned*)Hq);
    quant_transpose_pack_kernel<<<(DH / 64) * (DOUT / 64), 256, 0, stream>>>(
        w2, DH, DOUT, amax + 3, Wq);

    // out = Q(h) @ Q(w2) + b2                                   [32x32 arm]
    gemm_fp4_s32<0, 0><<<(B / 128) * (DOUT / 128), 256, 0, stream>>>(
        Hq, Wq, out, b2, amax + 2, amax + 3, nullptr, B, DOUT, DH);
}

// Round 11
// 709.716 us; speedup vs baseline: 1.1044x; 1.0008x over previous
//
#include <hip/hip_runtime.h>
#include <hip/hip_bf16.h>

// FP4 fake-quant MLP via MX-FP4 MFMA (16x16x128, unit block scales).
// Round 11: consolidation of per-GEMM winners + L3-adjacent elementwise order.
//   GEMM1 (M4096 N16384 K4096):  r2 structure (BK=256, single-buffer, 196us)
//   GEMM2 (M4096 N4096  K16384): r8-V1 structure (BK=128, dbuf, ~169us)
// Elementwise: per-tensor absmax immediately followed by its quant pass,
// quant passes traverse in REVERSE order so the L3-resident tail (just read
// by absmax / just written by GEMM1) is hit first (LRU-friendly re-read).

typedef float f32x4 __attribute__((ext_vector_type(4)));
typedef int   i32x4 __attribute__((ext_vector_type(4)));
typedef int   i32x8 __attribute__((ext_vector_type(8)));

#define AS1 __attribute__((address_space(1)))
#define AS3 __attribute__((address_space(3)))

// ---------- quant helpers ----------
__device__ __forceinline__ float scale_from_amax_bits(unsigned bits) {
    return fmaxf(__uint_as_float(bits) / 6.0f, 1e-12f);
}

// FP4 e2m1 code: idx 0..7 over grid {0,.5,1,1.5,2,3,4,6}, sign in bit 3.
// Compare chain == np.searchsorted(mids, xs, side='left') (ties -> lower mag).
__device__ __forceinline__ unsigned q4(float v, float inv_scale) {
    float xs = fabsf(v) * inv_scale;
    unsigned idx = 0;
    idx += (xs > 0.25f);
    idx += (xs > 0.75f);
    idx += (xs > 1.25f);
    idx += (xs > 1.75f);
    idx += (xs > 2.5f);
    idx += (xs > 3.5f);
    idx += (xs > 5.0f);
    return idx | ((v < 0.0f) ? 8u : 0u);
}

// ---------- tiny utility kernels ----------
__global__ void zero4_kernel(unsigned* p) {
    if (threadIdx.x < 4) p[threadIdx.x] = 0u;
}

__global__ void sentinel_kernel(float* out, long long n) {
    long long i = (long long)blockIdx.x * blockDim.x + threadIdx.x;
    long long stride = (long long)gridDim.x * blockDim.x;
    for (; i < n; i += stride) out[i] = 1e30f;
}

// ---------- absmax reduction (n % 4 == 0) ----------
__global__ void absmax_kernel(const float* __restrict__ in, long long n,
                              unsigned* __restrict__ out) {
    long long i = ((long long)blockIdx.x * blockDim.x + threadIdx.x) * 4;
    long long stride = (long long)gridDim.x * blockDim.x * 4;
    float m = 0.0f;
    for (; i < n; i += stride) {
        float4 v = *(const float4*)&in[i];
        m = fmaxf(m, fmaxf(fmaxf(fabsf(v.x), fabsf(v.y)),
                           fmaxf(fabsf(v.z), fabsf(v.w))));
    }
    #pragma unroll
    for (int off = 32; off > 0; off >>= 1)
        m = fmaxf(m, __shfl_xor(m, off));
    __shared__ float smax[4];
    int lane = threadIdx.x & 63, w = threadIdx.x >> 6;
    if (lane == 0) smax[w] = m;
    __syncthreads();
    if (threadIdx.x == 0) {
        m = fmaxf(fmaxf(smax[0], smax[1]), fmaxf(smax[2], smax[3]));
        atomicMax(out, __float_as_uint(m));  // valid: all values >= 0
    }
}

// ---------- quantize f32 -> packed fp4, REVERSED traversal (n % 8 == 0) -----
__global__ void quant_pack_rev_kernel(const float* __restrict__ in, long long n,
                                      const unsigned* __restrict__ amax,
                                      unsigned* __restrict__ out) {
    float inv = 1.0f / scale_from_amax_bits(*amax);
    long long nw = n >> 3;
    long long gid = (long long)blockIdx.x * blockDim.x + threadIdx.x;
    long long gs = (long long)gridDim.x * blockDim.x;
    for (long long j = nw - 1 - gid; j >= 0; j -= gs) {
        long long i = j * 8;
        float4 a = *(const float4*)&in[i];
        float4 b = *(const float4*)&in[i + 4];
        unsigned u = q4(a.x, inv)        | (q4(a.y, inv) << 4)
                   | (q4(a.z, inv) << 8) | (q4(a.w, inv) << 12)
                   | (q4(b.x, inv) << 16)| (q4(b.y, inv) << 20)
                   | (q4(b.z, inv) << 24)| (q4(b.w, inv) << 28);
        out[j] = u;
    }
}

// ---------- quantize + transpose + pack, REVERSED tile order ---------------
// in [R][C] f32 -> out [C][R/2] bytes. 64x64 tiles, 256 threads.
__global__ void quant_transpose_pack_kernel(const float* __restrict__ in, int R, int C,
                                            const unsigned* __restrict__ amax,
                                            unsigned char* __restrict__ out) {
    __shared__ float tile[64][65];
    float inv = 1.0f / scale_from_amax_bits(*amax);
    int t = threadIdx.x;
    int bid = gridDim.x - 1 - blockIdx.x;   // reverse: L3-resident tail first
    int CT = C >> 6;
    int tc = bid % CT;
    int tr = bid / CT;
    int r0 = t >> 4;            // 0..15
    int c0 = (t & 15) * 4;      // 0..60
    #pragma unroll
    for (int it = 0; it < 4; ++it) {
        int r = r0 + it * 16;
        float4 v = *(const float4*)&in[(size_t)(tr * 64 + r) * C + tc * 64 + c0];
        tile[r][c0 + 0] = v.x;
        tile[r][c0 + 1] = v.y;
        tile[r][c0 + 2] = v.z;
        tile[r][c0 + 3] = v.w;
    }
    __syncthreads();
    int c = t >> 2;             // 0..63 : output row (= input column)
    int rch = (t & 3) * 16;     // k-chunk of 16 values
    unsigned u0 = 0, u1 = 0;
    #pragma unroll
    for (int j = 0; j < 8; ++j) u0 |= q4(tile[rch + j][c], inv) << (4 * j);
    #pragma unroll
    for (int j = 0; j < 8; ++j) u1 |= q4(tile[rch + 8 + j][c], inv) << (4 * j);
    uint2 o; o.x = u0; o.y = u1;
    *(uint2*)&out[(size_t)(tc * 64 + c) * (R >> 1) + (size_t)(tr * 32) + (rch >> 1)] = o;
}

// ---------- fp4 MFMA helper ----------
__device__ __forceinline__ f32x4 mm16(i32x4 a, i32x4 b, f32x4 c) {
    i32x8 a8 = {a[0], a[1], a[2], a[3], 0, 0, 0, 0};
    i32x8 b8 = {b[0], b[1], b[2], b[3], 0, 0, 0, 0};
    return __builtin_amdgcn_mfma_scale_f32_16x16x128_f8f6f4(
        a8, b8, c, 4, 4, 0, 0x7f7f7f7f, 0, 0x7f7f7f7f);
}

#define AMAX_EPILOG                                                           \
    if (FUSE_AMAX) {                                                          \
        _Pragma("unroll")                                                     \
        for (int off = 32; off > 0; off >>= 1)                                \
            vmax = fmaxf(vmax, __shfl_xor(vmax, off));                        \
        if (lane == 0) smax[wid] = vmax;                                      \
        __syncthreads();                                                      \
        if (tid == 0) {                                                       \
            vmax = fmaxf(fmaxf(smax[0], smax[1]), fmaxf(smax[2], smax[3]));   \
            atomicMax(amaxOut, __float_as_uint(vmax));                        \
        }                                                                     \
    }

// ====== g1: r2 structure — 128x128 block, BK=256, single-buffer 32KB ========
// (best measured on GEMM1: 196us @ r2)
template <int RELU, int FUSE_AMAX>
__global__ __launch_bounds__(256, 2)
void gemm_fp4_g1(const unsigned char* __restrict__ Ap,
                 const unsigned char* __restrict__ Bp,
                 float* __restrict__ C, const float* __restrict__ bias,
                 const unsigned* __restrict__ amaxA,
                 const unsigned* __restrict__ amaxB,
                 unsigned* __restrict__ amaxOut,
                 int M, int N, int K) {
    __shared__ alignas(16) unsigned char As[128 * 128];  // 16 KB
    __shared__ alignas(16) unsigned char Bs[128 * 128];  // 16 KB
    __shared__ float smax[4];

    int nwg = gridDim.x, cpx = nwg >> 3;
    int wg = (blockIdx.x & 7) * cpx + (blockIdx.x >> 3);
    int MT = M >> 7;
    int tm = wg % MT, tn = wg / MT;

    int tid = threadIdx.x, lane = tid & 63, wid = tid >> 6;
    int wr = wid >> 1, wc = wid & 1;

    size_t Kb = (size_t)(K >> 1);

    int cs = ((lane & 7) ^ ((lane >> 3) & 7)) << 4;
    int srow = wid * 32 + (lane >> 3);
    const unsigned char* Abase = Ap + (size_t)(tm * 128 + srow) * Kb + cs;
    const unsigned char* Bbase = Bp + (size_t)(tn * 128 + srow) * Kb + cs;
    char* AsB = (char*)As;
    char* BsB = (char*)Bs;
    int ldsOff = wid * 4096;

    f32x4 acc[4][4] = {};
    int rrA = wr * 64 + (lane & 15);
    int rrB = wc * 64 + (lane & 15);

    int KT = K >> 8;
    for (int kt = 0; kt < KT; ++kt) {
        #pragma unroll
        for (int i = 0; i < 4; ++i) {
            __builtin_amdgcn_global_load_lds(
                (const AS1 void*)(Abase + (size_t)kt * 128 + (size_t)(i * 8) * Kb),
                (AS3 void*)(AsB + ldsOff + i * 1024), 16, 0, 0);
            __builtin_amdgcn_global_load_lds(
                (const AS1 void*)(Bbase + (size_t)kt * 128 + (size_t)(i * 8) * Kb),
                (AS3 void*)(BsB + ldsOff + i * 1024), 16, 0, 0);
        }
        __syncthreads();

        #pragma unroll
        for (int ks = 0; ks < 2; ++ks) {
            int slotOff = ((ks * 4 + (lane >> 4)) ^ (lane & 7)) << 4;
            i32x4 a[4], b[4];
            #pragma unroll
            for (int mi = 0; mi < 4; ++mi)
                a[mi] = *(const i32x4*)(AsB + (rrA + mi * 16) * 128 + slotOff);
            #pragma unroll
            for (int ni = 0; ni < 4; ++ni)
                b[ni] = *(const i32x4*)(BsB + (rrB + ni * 16) * 128 + slotOff);
            #pragma unroll
            for (int mi = 0; mi < 4; ++mi)
                #pragma unroll
                for (int ni = 0; ni < 4; ++ni)
                    acc[mi][ni] = mm16(a[mi], b[ni], acc[mi][ni]);
        }
        __syncthreads();
    }

    float s = scale_from_amax_bits(*amaxA) * scale_from_amax_bits(*amaxB);
    float vmax = 0.0f;
    int rowBase = tm * 128 + wr * 64 + (lane >> 4) * 4;
    int colBase = tn * 128 + wc * 64 + (lane & 15);
    #pragma unroll
    for (int mi = 0; mi < 4; ++mi) {
        #pragma unroll
        for (int ni = 0; ni < 4; ++ni) {
            int col = colBase + ni * 16;
            float bv = bias[col];
            int row = rowBase + mi * 16;
            #pragma unroll
            for (int r = 0; r < 4; ++r) {
                float v = acc[mi][ni][r] * s + bv;
                if (RELU) v = fmaxf(v, 0.0f);
                if (FUSE_AMAX) vmax = fmaxf(vmax, fabsf(v));
                C[(size_t)(row + r) * N + col] = v;
            }
        }
    }
    AMAX_EPILOG
}

// ====== g2: r8-V1 structure — 128x128 block, BK=128, dbuf 32KB ==============
// (best measured on GEMM2: ~169us residual @ r8)
template <int RELU, int FUSE_AMAX>
__global__ __launch_bounds__(256, 2)
void gemm_fp4_g2(const unsigned char* __restrict__ Ap,
                 const unsigned char* __restrict__ Bp,
                 float* __restrict__ C, const float* __restrict__ bias,
                 const unsigned* __restrict__ amaxA,
                 const unsigned* __restrict__ amaxB,
                 unsigned* __restrict__ amaxOut,
                 int M, int N, int K) {
    __shared__ alignas(16) unsigned char As[2][128 * 64];  // 16 KB
    __shared__ alignas(16) unsigned char Bs[2][128 * 64];  // 16 KB
    __shared__ float smax[4];

    int nwg = gridDim.x, cpx = nwg >> 3;
    int wg = (blockIdx.x & 7) * cpx + (blockIdx.x >> 3);
    int MT = M >> 7;
    int tm = wg % MT, tn = wg / MT;

    int tid = threadIdx.x, lane = tid & 63, wid = tid >> 6;
    int wr = wid >> 1, wc = wid & 1;

    size_t Kb = (size_t)(K >> 1);

    // BK=128 swizzle: LDS slot = chunk ^ ((row>>1)&3); pre-swizzled source.
    int csw = ((tid & 3) ^ ((tid >> 3) & 3)) << 4;
    int srow = tid >> 2;                // 0..63
    const unsigned char* Abase = Ap + (size_t)(tm * 128 + srow) * Kb + csw;
    const unsigned char* Bbase = Bp + (size_t)(tn * 128 + srow) * Kb + csw;
    char* AsB = (char*)As;
    char* BsB = (char*)Bs;
    int dstOff = wid << 10;

#define STAGE_G2(d, kt)                                                       \
    do {                                                                      \
        _Pragma("unroll")                                                     \
        for (int i_ = 0; i_ < 2; ++i_) {                                      \
            __builtin_amdgcn_global_load_lds(                                 \
                (const AS1 void*)(Abase + (size_t)(kt) * 64 +                 \
                                  (size_t)(i_ * 64) * Kb),                    \
                (AS3 void*)(AsB + ((d) << 13) + (i_ << 12) + dstOff),         \
                16, 0, 0);                                                    \
            __builtin_amdgcn_global_load_lds(                                 \
                (const AS1 void*)(Bbase + (size_t)(kt) * 64 +                 \
                                  (size_t)(i_ * 64) * Kb),                    \
                (AS3 void*)(BsB + ((d) << 13) + (i_ << 12) + dstOff),         \
                16, 0, 0);                                                    \
        }                                                                     \
    } while (0)

    f32x4 acc[4][4] = {};
    int rrA = wr * 64 + (lane & 15);
    int rrB = wc * 64 + (lane & 15);
    int slotOff = (((lane >> 4) ^ ((lane >> 1) & 3)) << 4);

    int KT = K >> 7;
    STAGE_G2(0, 0);
    __syncthreads();

    for (int t = 0; t < KT; ++t) {
        int d = t & 1;
        if (t + 1 < KT) STAGE_G2(d ^ 1, t + 1);
        __builtin_amdgcn_sched_barrier(0);

        const char* Aq = AsB + (d << 13);
        const char* Bq = BsB + (d << 13);
        i32x4 a[4], b[4];
        #pragma unroll
        for (int mi = 0; mi < 4; ++mi)
            a[mi] = *(const i32x4*)(Aq + (rrA + mi * 16) * 64 + slotOff);
        #pragma unroll
        for (int ni = 0; ni < 4; ++ni)
            b[ni] = *(const i32x4*)(Bq + (rrB + ni * 16) * 64 + slotOff);
        #pragma unroll
        for (int mi = 0; mi < 4; ++mi)
            #pragma unroll
            for (int ni = 0; ni < 4; ++ni)
                acc[mi][ni] = mm16(a[mi], b[ni], acc[mi][ni]);
        __syncthreads();
    }
#undef STAGE_G2

    float s = scale_from_amax_bits(*amaxA) * scale_from_amax_bits(*amaxB);
    float vmax = 0.0f;
    int rowBase = tm * 128 + wr * 64 + (lane >> 4) * 4;
    int colBase = tn * 128 + wc * 64 + (lane & 15);
    #pragma unroll
    for (int mi = 0; mi < 4; ++mi) {
        #pragma unroll
        for (int ni = 0; ni < 4; ++ni) {
            int col = colBase + ni * 16;
            float bv = bias[col];
            int row = rowBase + mi * 16;
            #pragma unroll
            for (int r = 0; r < 4; ++r) {
                float v = acc[mi][ni][r] * s + bv;
                if (RELU) v = fmaxf(v, 0.0f);
                if (FUSE_AMAX) vmax = fmaxf(vmax, fabsf(v));
                C[(size_t)(row + r) * N + col] = v;
            }
        }
    }
    AMAX_EPILOG
}

// ---------- launch ----------
extern "C" void kernel_launch(void* const* d_in, const int* in_sizes, int n_in,
                              void* d_out, int out_size, void* d_ws, size_t ws_size,
                              hipStream_t stream) {
    const float* x  = (const float*)d_in[0];
    const float* w1 = (const float*)d_in[1];
    const float* b1 = (const float*)d_in[2];
    const float* w2 = (const float*)d_in[3];
    const float* b2 = (const float*)d_in[4];
    float* out = (float*)d_out;

    const int B = 4096, DIN = 4096, DH = 16384, DOUT = 4096;

    const size_t off_amax = 0;                                    // 4 uints
    const size_t off_Xq   = 256;                                  // 8 MB
    const size_t off_W    = off_Xq + (size_t)B * DIN / 2;         // 32 MB
    const size_t off_h    = off_W + (size_t)DIN * DH / 2;         // 256 MB f32
    const size_t off_Hq   = off_h + (size_t)B * DH * 4;           // 32 MB
    const size_t needed   = off_Hq + (size_t)B * DH / 2;

    if (ws_size < needed) {
        sentinel_kernel<<<2048, 256, 0, stream>>>(out, (long long)out_size);
        return;
    }

    char* ws = (char*)d_ws;
    unsigned* amax = (unsigned*)(ws + off_amax);  // [0]=x [1]=w1 [2]=h [3]=w2
    unsigned char* Xq = (unsigned char*)(ws + off_Xq);
    unsigned char* Wq = (unsigned char*)(ws + off_W);
    float*         h  = (float*)(ws + off_h);
    unsigned char* Hq = (unsigned char*)(ws + off_Hq);

    zero4_kernel<<<1, 64, 0, stream>>>(amax);

    // --- w1: absmax then immediate reversed re-read (L3-adjacent) ---
    absmax_kernel<<<2048, 256, 0, stream>>>(w1, (long long)DIN * DH, amax + 1);
    quant_transpose_pack_kernel<<<(DIN / 64) * (DH / 64), 256, 0, stream>>>(
        w1, DIN, DH, amax + 1, Wq);

    // --- x: absmax then immediate quant (64MB, L3-resident) ---
    absmax_kernel<<<2048, 256, 0, stream>>>(x, (long long)B * DIN, amax + 0);
    quant_pack_rev_kernel<<<2048, 256, 0, stream>>>(x, (long long)B * DIN,
                                                    amax + 0, (unsigned*)Xq);

    // h = relu(Q(x) @ Q(w1) + b1), fused absmax(h) -> amax[2]
    gemm_fp4_g1<1, 1><<<(B / 128) * (DH / 128), 256, 0, stream>>>(
        Xq, Wq, h, b1, amax + 0, amax + 1, amax + 2, B, DH, DIN);

    // --- h: quant immediately after GEMM1 (h tail L3-resident), reversed ---
    quant_pack_rev_kernel<<<2048, 256, 0, stream>>>(h, (long long)B * DH,
                                                    amax + 2, (unsigned*)Hq);

    // --- w2: absmax then immediate reversed re-read (L3-adjacent) ---
    absmax_kernel<<<2048, 256, 0, stream>>>(w2, (long long)DH * DOUT, amax + 3);
    quant_transpose_pack_kernel<<<(DH / 64) * (DOUT / 64), 256, 0, stream>>>(
        w2, DH, DOUT, amax + 3, Wq);

    // out = Q(h) @ Q(w2) + b2
    gemm_fp4_g2<0, 0><<<(B / 128) * (DOUT / 128), 256, 0, stream>>>(
        Hq, Wq, out, b2, amax + 2, amax + 3, nullptr, B, DOUT, DH);
}

// Round 13
// 669.979 us; speedup vs baseline: 1.1699x; 1.0593x over previous
//
#include <hip/hip_runtime.h>
#include <hip/hip_bf16.h>

// FP4 fake-quant MLP via MX-FP4 MFMA (16x16x128, unit block scales).
// Round 13 = round 12 with the compile fix: __builtin_nontemporal_load needs a
// NATIVE vector type (ext_vector_type), not HIP's float4 struct.
// Theory under test (r11 counters): GEMM1 fetches 397MB for 40MB of operands
// because the 256MB h-write stream evicts Xq/Wq from L2/L3. NT stores for
// pure output streams (h, out) + NT loads for last-use reads (quant passes)
// keep the GEMM operand working set cache-resident.
//   GEMM1 (M4096 N16384 K4096):  r2 structure (BK=256, single-buffer)
//   GEMM2 (M4096 N4096  K16384): r8-V1 structure (BK=128, dbuf)

typedef float f32x4  __attribute__((ext_vector_type(4)));
typedef int   i32x4  __attribute__((ext_vector_type(4)));
typedef int   i32x8  __attribute__((ext_vector_type(8)));

#define AS1 __attribute__((address_space(1)))
#define AS3 __attribute__((address_space(3)))

// ---------- quant helpers ----------
__device__ __forceinline__ float scale_from_amax_bits(unsigned bits) {
    return fmaxf(__uint_as_float(bits) / 6.0f, 1e-12f);
}

// FP4 e2m1 code: idx 0..7 over grid {0,.5,1,1.5,2,3,4,6}, sign in bit 3.
// Compare chain == np.searchsorted(mids, xs, side='left') (ties -> lower mag).
__device__ __forceinline__ unsigned q4(float v, float inv_scale) {
    float xs = fabsf(v) * inv_scale;
    unsigned idx = 0;
    idx += (xs > 0.25f);
    idx += (xs > 0.75f);
    idx += (xs > 1.25f);
    idx += (xs > 1.75f);
    idx += (xs > 2.5f);
    idx += (xs > 3.5f);
    idx += (xs > 5.0f);
    return idx | ((v < 0.0f) ? 8u : 0u);
}

// ---------- tiny utility kernels ----------
__global__ void zero4_kernel(unsigned* p) {
    if (threadIdx.x < 4) p[threadIdx.x] = 0u;
}

__global__ void sentinel_kernel(float* out, long long n) {
    long long i = (long long)blockIdx.x * blockDim.x + threadIdx.x;
    long long stride = (long long)gridDim.x * blockDim.x;
    for (; i < n; i += stride) out[i] = 1e30f;
}

// ---------- absmax reduction (n % 4 == 0); first read -> normal (cache) -----
__global__ void absmax_kernel(const float* __restrict__ in, long long n,
                              unsigned* __restrict__ out) {
    long long i = ((long long)blockIdx.x * blockDim.x + threadIdx.x) * 4;
    long long stride = (long long)gridDim.x * blockDim.x * 4;
    float m = 0.0f;
    for (; i < n; i += stride) {
        f32x4 v = *(const f32x4*)&in[i];
        m = fmaxf(m, fmaxf(fmaxf(fabsf(v.x), fabsf(v.y)),
                           fmaxf(fabsf(v.z), fabsf(v.w))));
    }
    #pragma unroll
    for (int off = 32; off > 0; off >>= 1)
        m = fmaxf(m, __shfl_xor(m, off));
    __shared__ float smax[4];
    int lane = threadIdx.x & 63, w = threadIdx.x >> 6;
    if (lane == 0) smax[w] = m;
    __syncthreads();
    if (threadIdx.x == 0) {
        m = fmaxf(fmaxf(smax[0], smax[1]), fmaxf(smax[2], smax[3]));
        atomicMax(out, __float_as_uint(m));  // valid: all values >= 0
    }
}

// ---------- quantize f32 -> packed fp4, reversed, NT loads (last use) -------
__global__ void quant_pack_rev_kernel(const float* __restrict__ in, long long n,
                                      const unsigned* __restrict__ amax,
                                      unsigned* __restrict__ out) {
    float inv = 1.0f / scale_from_amax_bits(*amax);
    long long nw = n >> 3;
    long long gid = (long long)blockIdx.x * blockDim.x + threadIdx.x;
    long long gs = (long long)gridDim.x * blockDim.x;
    for (long long j = nw - 1 - gid; j >= 0; j -= gs) {
        long long i = j * 8;
        f32x4 a = __builtin_nontemporal_load((const f32x4*)&in[i]);
        f32x4 b = __builtin_nontemporal_load((const f32x4*)&in[i + 4]);
        unsigned u = q4(a.x, inv)        | (q4(a.y, inv) << 4)
                   | (q4(a.z, inv) << 8) | (q4(a.w, inv) << 12)
                   | (q4(b.x, inv) << 16)| (q4(b.y, inv) << 20)
                   | (q4(b.z, inv) << 24)| (q4(b.w, inv) << 28);
        out[j] = u;   // normal store: re-read by the GEMM soon
    }
}

// ---------- quantize + transpose + pack, reversed tiles, NT loads ----------
// in [R][C] f32 -> out [C][R/2] bytes. 64x64 tiles, 256 threads.
__global__ void quant_transpose_pack_kernel(const float* __restrict__ in, int R, int C,
                                            const unsigned* __restrict__ amax,
                                            unsigned char* __restrict__ out) {
    __shared__ float tile[64][65];
    float inv = 1.0f / scale_from_amax_bits(*amax);
    int t = threadIdx.x;
    int bid = gridDim.x - 1 - blockIdx.x;   // reverse: L3-resident tail first
    int CT = C >> 6;
    int tc = bid % CT;
    int tr = bid / CT;
    int r0 = t >> 4;            // 0..15
    int c0 = (t & 15) * 4;      // 0..60
    #pragma unroll
    for (int it = 0; it < 4; ++it) {
        int r = r0 + it * 16;
        f32x4 v = __builtin_nontemporal_load(
            (const f32x4*)&in[(size_t)(tr * 64 + r) * C + tc * 64 + c0]);
        tile[r][c0 + 0] = v.x;
        tile[r][c0 + 1] = v.y;
        tile[r][c0 + 2] = v.z;
        tile[r][c0 + 3] = v.w;
    }
    __syncthreads();
    int c = t >> 2;             // 0..63 : output row (= input column)
    int rch = (t & 3) * 16;     // k-chunk of 16 values
    unsigned u0 = 0, u1 = 0;
    #pragma unroll
    for (int j = 0; j < 8; ++j) u0 |= q4(tile[rch + j][c], inv) << (4 * j);
    #pragma unroll
    for (int j = 0; j < 8; ++j) u1 |= q4(tile[rch + 8 + j][c], inv) << (4 * j);
    uint2 o; o.x = u0; o.y = u1;
    *(uint2*)&out[(size_t)(tc * 64 + c) * (R >> 1) + (size_t)(tr * 32) + (rch >> 1)] = o;
}

// ---------- fp4 MFMA helper ----------
__device__ __forceinline__ f32x4 mm16(i32x4 a, i32x4 b, f32x4 c) {
    i32x8 a8 = {a[0], a[1], a[2], a[3], 0, 0, 0, 0};
    i32x8 b8 = {b[0], b[1], b[2], b[3], 0, 0, 0, 0};
    return __builtin_amdgcn_mfma_scale_f32_16x16x128_f8f6f4(
        a8, b8, c, 4, 4, 0, 0x7f7f7f7f, 0, 0x7f7f7f7f);
}

#define AMAX_EPILOG                                                           \
    if (FUSE_AMAX) {                                                          \
        _Pragma("unroll")                                                     \
        for (int off = 32; off > 0; off >>= 1)                                \
            vmax = fmaxf(vmax, __shfl_xor(vmax, off));                        \
        if (lane == 0) smax[wid] = vmax;                                      \
        __syncthreads();                                                      \
        if (tid == 0) {                                                       \
            vmax = fmaxf(fmaxf(smax[0], smax[1]), fmaxf(smax[2], smax[3]));   \
            atomicMax(amaxOut, __float_as_uint(vmax));                        \
        }                                                                     \
    }

// ====== g1: r2 structure — 128x128 block, BK=256, single-buffer 32KB ========
// + NT store of C (h): output stream must not evict Xq/Wq from L2/L3.
template <int RELU, int FUSE_AMAX>
__global__ __launch_bounds__(256, 2)
void gemm_fp4_g1(const unsigned char* __restrict__ Ap,
                 const unsigned char* __restrict__ Bp,
                 float* __restrict__ C, const float* __restrict__ bias,
                 const unsigned* __restrict__ amaxA,
                 const unsigned* __restrict__ amaxB,
                 unsigned* __restrict__ amaxOut,
                 int M, int N, int K) {
    __shared__ alignas(16) unsigned char As[128 * 128];  // 16 KB
    __shared__ alignas(16) unsigned char Bs[128 * 128];  // 16 KB
    __shared__ float smax[4];

    int nwg = gridDim.x, cpx = nwg >> 3;
    int wg = (blockIdx.x & 7) * cpx + (blockIdx.x >> 3);
    int MT = M >> 7;
    int tm = wg % MT, tn = wg / MT;

    int tid = threadIdx.x, lane = tid & 63, wid = tid >> 6;
    int wr = wid >> 1, wc = wid & 1;

    size_t Kb = (size_t)(K >> 1);

    int cs = ((lane & 7) ^ ((lane >> 3) & 7)) << 4;
    int srow = wid * 32 + (lane >> 3);
    const unsigned char* Abase = Ap + (size_t)(tm * 128 + srow) * Kb + cs;
    const unsigned char* Bbase = Bp + (size_t)(tn * 128 + srow) * Kb + cs;
    char* AsB = (char*)As;
    char* BsB = (char*)Bs;
    int ldsOff = wid * 4096;

    f32x4 acc[4][4] = {};
    int rrA = wr * 64 + (lane & 15);
    int rrB = wc * 64 + (lane & 15);

    int KT = K >> 8;
    for (int kt = 0; kt < KT; ++kt) {
        #pragma unroll
        for (int i = 0; i < 4; ++i) {
            __builtin_amdgcn_global_load_lds(
                (const AS1 void*)(Abase + (size_t)kt * 128 + (size_t)(i * 8) * Kb),
                (AS3 void*)(AsB + ldsOff + i * 1024), 16, 0, 0);
            __builtin_amdgcn_global_load_lds(
                (const AS1 void*)(Bbase + (size_t)kt * 128 + (size_t)(i * 8) * Kb),
                (AS3 void*)(BsB + ldsOff + i * 1024), 16, 0, 0);
        }
        __syncthreads();

        #pragma unroll
        for (int ks = 0; ks < 2; ++ks) {
            int slotOff = ((ks * 4 + (lane >> 4)) ^ (lane & 7)) << 4;
            i32x4 a[4], b[4];
            #pragma unroll
            for (int mi = 0; mi < 4; ++mi)
                a[mi] = *(const i32x4*)(AsB + (rrA + mi * 16) * 128 + slotOff);
            #pragma unroll
            for (int ni = 0; ni < 4; ++ni)
                b[ni] = *(const i32x4*)(BsB + (rrB + ni * 16) * 128 + slotOff);
            #pragma unroll
            for (int mi = 0; mi < 4; ++mi)
                #pragma unroll
                for (int ni = 0; ni < 4; ++ni)
                    acc[mi][ni] = mm16(a[mi], b[ni], acc[mi][ni]);
        }
        __syncthreads();
    }

    float s = scale_from_amax_bits(*amaxA) * scale_from_amax_bits(*amaxB);
    float vmax = 0.0f;
    int rowBase = tm * 128 + wr * 64 + (lane >> 4) * 4;
    int colBase = tn * 128 + wc * 64 + (lane & 15);
    #pragma unroll
    for (int mi = 0; mi < 4; ++mi) {
        #pragma unroll
        for (int ni = 0; ni < 4; ++ni) {
            int col = colBase + ni * 16;
            float bv = bias[col];
            int row = rowBase + mi * 16;
            #pragma unroll
            for (int r = 0; r < 4; ++r) {
                float v = acc[mi][ni][r] * s + bv;
                if (RELU) v = fmaxf(v, 0.0f);
                if (FUSE_AMAX) vmax = fmaxf(vmax, fabsf(v));
                __builtin_nontemporal_store(v, &C[(size_t)(row + r) * N + col]);
            }
        }
    }
    AMAX_EPILOG
}

// ====== g2: r8-V1 structure — 128x128 block, BK=128, dbuf 32KB ==============
// + NT store of C (out).
template <int RELU, int FUSE_AMAX>
__global__ __launch_bounds__(256, 2)
void gemm_fp4_g2(const unsigned char* __restrict__ Ap,
                 const unsigned char* __restrict__ Bp,
                 float* __restrict__ C, const float* __restrict__ bias,
                 const unsigned* __restrict__ amaxA,
                 const unsigned* __restrict__ amaxB,
                 unsigned* __restrict__ amaxOut,
                 int M, int N, int K) {
    __shared__ alignas(16) unsigned char As[2][128 * 64];  // 16 KB
    __shared__ alignas(16) unsigned char Bs[2][128 * 64];  // 16 KB
    __shared__ float smax[4];

    int nwg = gridDim.x, cpx = nwg >> 3;
    int wg = (blockIdx.x & 7) * cpx + (blockIdx.x >> 3);
    int MT = M >> 7;
    int tm = wg % MT, tn = wg / MT;

    int tid = threadIdx.x, lane = tid & 63, wid = tid >> 6;
    int wr = wid >> 1, wc = wid & 1;

    size_t Kb = (size_t)(K >> 1);

    // BK=128 swizzle: LDS slot = chunk ^ ((row>>1)&3); pre-swizzled source.
    int csw = ((tid & 3) ^ ((tid >> 3) & 3)) << 4;
    int srow = tid >> 2;                // 0..63
    const unsigned char* Abase = Ap + (size_t)(tm * 128 + srow) * Kb + csw;
    const unsigned char* Bbase = Bp + (size_t)(tn * 128 + srow) * Kb + csw;
    char* AsB = (char*)As;
    char* BsB = (char*)Bs;
    int dstOff = wid << 10;

#define STAGE_G2(d, kt)                                                       \
    do {                                                                      \
        _Pragma("unroll")                                                     \
        for (int i_ = 0; i_ < 2; ++i_) {                                      \
            __builtin_amdgcn_global_load_lds(                                 \
                (const AS1 void*)(Abase + (size_t)(kt) * 64 +                 \
                                  (size_t)(i_ * 64) * Kb),                    \
                (AS3 void*)(AsB + ((d) << 13) + (i_ << 12) + dstOff),         \
                16, 0, 0);                                                    \
            __builtin_amdgcn_global_load_lds(                                 \
                (const AS1 void*)(Bbase + (size_t)(kt) * 64 +                 \
                                  (size_t)(i_ * 64) * Kb),                    \
                (AS3 void*)(BsB + ((d) << 13) + (i_ << 12) + dstOff),         \
                16, 0, 0);                                                    \
        }                                                                     \
    } while (0)

    f32x4 acc[4][4] = {};
    int rrA = wr * 64 + (lane & 15);
    int rrB = wc * 64 + (lane & 15);
    int slotOff = (((lane >> 4) ^ ((lane >> 1) & 3)) << 4);

    int KT = K >> 7;
    STAGE_G2(0, 0);
    __syncthreads();

    for (int t = 0; t < KT; ++t) {
        int d = t & 1;
        if (t + 1 < KT) STAGE_G2(d ^ 1, t + 1);
        __builtin_amdgcn_sched_barrier(0);

        const char* Aq = AsB + (d << 13);
        const char* Bq = BsB + (d << 13);
        i32x4 a[4], b[4];
        #pragma unroll
        for (int mi = 0; mi < 4; ++mi)
            a[mi] = *(const i32x4*)(Aq + (rrA + mi * 16) * 64 + slotOff);
        #pragma unroll
        for (int ni = 0; ni < 4; ++ni)
            b[ni] = *(const i32x4*)(Bq + (rrB + ni * 16) * 64 + slotOff);
        #pragma unroll
        for (int mi = 0; mi < 4; ++mi)
            #pragma unroll
            for (int ni = 0; ni < 4; ++ni)
                acc[mi][ni] = mm16(a[mi], b[ni], acc[mi][ni]);
        __syncthreads();
    }
#undef STAGE_G2

    float s = scale_from_amax_bits(*amaxA) * scale_from_amax_bits(*amaxB);
    float vmax = 0.0f;
    int rowBase = tm * 128 + wr * 64 + (lane >> 4) * 4;
    int colBase = tn * 128 + wc * 64 + (lane & 15);
    #pragma unroll
    for (int mi = 0; mi < 4; ++mi) {
        #pragma unroll
        for (int ni = 0; ni < 4; ++ni) {
            int col = colBase + ni * 16;
            float bv = bias[col];
            int row = rowBase + mi * 16;
            #pragma unroll
            for (int r = 0; r < 4; ++r) {
                float v = acc[mi][ni][r] * s + bv;
                if (RELU) v = fmaxf(v, 0.0f);
                if (FUSE_AMAX) vmax = fmaxf(vmax, fabsf(v));
                __builtin_nontemporal_store(v, &C[(size_t)(row + r) * N + col]);
            }
        }
    }
    AMAX_EPILOG
}

// ---------- launch ----------
extern "C" void kernel_launch(void* const* d_in, const int* in_sizes, int n_in,
                              void* d_out, int out_size, void* d_ws, size_t ws_size,
                              hipStream_t stream) {
    const float* x  = (const float*)d_in[0];
    const float* w1 = (const float*)d_in[1];
    const float* b1 = (const float*)d_in[2];
    const float* w2 = (const float*)d_in[3];
    const float* b2 = (const float*)d_in[4];
    float* out = (float*)d_out;

    const int B = 4096, DIN = 4096, DH = 16384, DOUT = 4096;

    const size_t off_amax = 0;                                    // 4 uints
    const size_t off_Xq   = 256;                                  // 8 MB
    const size_t off_W    = off_Xq + (size_t)B * DIN / 2;         // 32 MB
    const size_t off_h    = off_W + (size_t)DIN * DH / 2;         // 256 MB f32
    const size_t off_Hq   = off_h + (size_t)B * DH * 4;           // 32 MB
    const size_t needed   = off_Hq + (size_t)B * DH / 2;

    if (ws_size < needed) {
        sentinel_kernel<<<2048, 256, 0, stream>>>(out, (long long)out_size);
        return;
    }

    char* ws = (char*)d_ws;
    unsigned* amax = (unsigned*)(ws + off_amax);  // [0]=x [1]=w1 [2]=h [3]=w2
    unsigned char* Xq = (unsigned char*)(ws + off_Xq);
    unsigned char* Wq = (unsigned char*)(ws + off_W);
    float*         h  = (float*)(ws + off_h);
    unsigned char* Hq = (unsigned char*)(ws + off_Hq);

    zero4_kernel<<<1, 64, 0, stream>>>(amax);

    // --- w1: absmax then immediate reversed re-read (L3-adjacent) ---
    absmax_kernel<<<2048, 256, 0, stream>>>(w1, (long long)DIN * DH, amax + 1);
    quant_transpose_pack_kernel<<<(DIN / 64) * (DH / 64), 256, 0, stream>>>(
        w1, DIN, DH, amax + 1, Wq);

    // --- x: absmax then immediate quant (64MB, L3-resident) ---
    absmax_kernel<<<2048, 256, 0, stream>>>(x, (long long)B * DIN, amax + 0);
    quant_pack_rev_kernel<<<2048, 256, 0, stream>>>(x, (long long)B * DIN,
                                                    amax + 0, (unsigned*)Xq);

    // h = relu(Q(x) @ Q(w1) + b1), fused absmax(h) -> amax[2]
    gemm_fp4_g1<1, 1><<<(B / 128) * (DH / 128), 256, 0, stream>>>(
        Xq, Wq, h, b1, amax + 0, amax + 1, amax + 2, B, DH, DIN);

    // --- h: quant immediately after GEMM1, reversed, NT loads ---
    quant_pack_rev_kernel<<<2048, 256, 0, stream>>>(h, (long long)B * DH,
                                                    amax + 2, (unsigned*)Hq);

    // --- w2: absmax then immediate reversed re-read (L3-adjacent) ---
    absmax_kernel<<<2048, 256, 0, stream>>>(w2, (long long)DH * DOUT, amax + 3);
    quant_transpose_pack_kernel<<<(DH / 64) * (DOUT / 64), 256, 0, stream>>>(
        w2, DH, DOUT, amax + 3, Wq);

    // out = Q(h) @ Q(w2) + b2
    gemm_fp4_g2<0, 0><<<(B / 128) * (DOUT / 128), 256, 0, stream>>>(
        Hq, Wq, out, b2, amax + 2, amax + 3, nullptr, B, DOUT, DH);
}

// Round 14
// 663.554 us; speedup vs baseline: 1.1813x; 1.0097x over previous
//
#include <hip/hip_runtime.h>
#include <hip/hip_bf16.h>

// FP4 fake-quant MLP via MX-FP4 MFMA (16x16x128, unit block scales).
// Round 14: g1 + elementwise byte-identical to r13 (control). g2 swapped to a
// faithful m201-style 4-phase/8-MFMA pipelined 256x256 kernel:
//  - BK=128 fp4 (64B rows) -> 64KB LDS, r8-proven 0-conflict XOR swizzle
//  - 2-tile-deep prefetch, counted vmcnt(4) (never 0 in main loop)
//  - every stage targets a slot whose reads RETIRED >=1 barrier earlier
//  - setprio(1) around each 8-MFMA cluster, lgkmcnt(0)+sched_barrier fences

typedef float f32x4  __attribute__((ext_vector_type(4)));
typedef int   i32x4  __attribute__((ext_vector_type(4)));
typedef int   i32x8  __attribute__((ext_vector_type(8)));

#define AS1 __attribute__((address_space(1)))
#define AS3 __attribute__((address_space(3)))

#define SB0   __builtin_amdgcn_sched_barrier(0)
#define BAR   __builtin_amdgcn_s_barrier()
#define LGKM0 asm volatile("s_waitcnt lgkmcnt(0)" ::: "memory")

// ---------- quant helpers ----------
__device__ __forceinline__ float scale_from_amax_bits(unsigned bits) {
    return fmaxf(__uint_as_float(bits) / 6.0f, 1e-12f);
}

// FP4 e2m1 code: idx 0..7 over grid {0,.5,1,1.5,2,3,4,6}, sign in bit 3.
__device__ __forceinline__ unsigned q4(float v, float inv_scale) {
    float xs = fabsf(v) * inv_scale;
    unsigned idx = 0;
    idx += (xs > 0.25f);
    idx += (xs > 0.75f);
    idx += (xs > 1.25f);
    idx += (xs > 1.75f);
    idx += (xs > 2.5f);
    idx += (xs > 3.5f);
    idx += (xs > 5.0f);
    return idx | ((v < 0.0f) ? 8u : 0u);
}

// ---------- tiny utility kernels ----------
__global__ void zero4_kernel(unsigned* p) {
    if (threadIdx.x < 4) p[threadIdx.x] = 0u;
}

__global__ void sentinel_kernel(float* out, long long n) {
    long long i = (long long)blockIdx.x * blockDim.x + threadIdx.x;
    long long stride = (long long)gridDim.x * blockDim.x;
    for (; i < n; i += stride) out[i] = 1e30f;
}

// ---------- absmax reduction (n % 4 == 0) ----------
__global__ void absmax_kernel(const float* __restrict__ in, long long n,
                              unsigned* __restrict__ out) {
    long long i = ((long long)blockIdx.x * blockDim.x + threadIdx.x) * 4;
    long long stride = (long long)gridDim.x * blockDim.x * 4;
    float m = 0.0f;
    for (; i < n; i += stride) {
        f32x4 v = *(const f32x4*)&in[i];
        m = fmaxf(m, fmaxf(fmaxf(fabsf(v.x), fabsf(v.y)),
                           fmaxf(fabsf(v.z), fabsf(v.w))));
    }
    #pragma unroll
    for (int off = 32; off > 0; off >>= 1)
        m = fmaxf(m, __shfl_xor(m, off));
    __shared__ float smax[4];
    int lane = threadIdx.x & 63, w = threadIdx.x >> 6;
    if (lane == 0) smax[w] = m;
    __syncthreads();
    if (threadIdx.x == 0) {
        m = fmaxf(fmaxf(smax[0], smax[1]), fmaxf(smax[2], smax[3]));
        atomicMax(out, __float_as_uint(m));  // valid: all values >= 0
    }
}

// ---------- quantize f32 -> packed fp4, reversed, NT loads (last use) -------
__global__ void quant_pack_rev_kernel(const float* __restrict__ in, long long n,
                                      const unsigned* __restrict__ amax,
                                      unsigned* __restrict__ out) {
    float inv = 1.0f / scale_from_amax_bits(*amax);
    long long nw = n >> 3;
    long long gid = (long long)blockIdx.x * blockDim.x + threadIdx.x;
    long long gs = (long long)gridDim.x * blockDim.x;
    for (long long j = nw - 1 - gid; j >= 0; j -= gs) {
        long long i = j * 8;
        f32x4 a = __builtin_nontemporal_load((const f32x4*)&in[i]);
        f32x4 b = __builtin_nontemporal_load((const f32x4*)&in[i + 4]);
        unsigned u = q4(a.x, inv)        | (q4(a.y, inv) << 4)
                   | (q4(a.z, inv) << 8) | (q4(a.w, inv) << 12)
                   | (q4(b.x, inv) << 16)| (q4(b.y, inv) << 20)
                   | (q4(b.z, inv) << 24)| (q4(b.w, inv) << 28);
        out[j] = u;
    }
}

// ---------- quantize + transpose + pack, reversed tiles, NT loads ----------
__global__ void quant_transpose_pack_kernel(const float* __restrict__ in, int R, int C,
                                            const unsigned* __restrict__ amax,
                                            unsigned char* __restrict__ out) {
    __shared__ float tile[64][65];
    float inv = 1.0f / scale_from_amax_bits(*amax);
    int t = threadIdx.x;
    int bid = gridDim.x - 1 - blockIdx.x;   // reverse: L3-resident tail first
    int CT = C >> 6;
    int tc = bid % CT;
    int tr = bid / CT;
    int r0 = t >> 4;
    int c0 = (t & 15) * 4;
    #pragma unroll
    for (int it = 0; it < 4; ++it) {
        int r = r0 + it * 16;
        f32x4 v = __builtin_nontemporal_load(
            (const f32x4*)&in[(size_t)(tr * 64 + r) * C + tc * 64 + c0]);
        tile[r][c0 + 0] = v.x;
        tile[r][c0 + 1] = v.y;
        tile[r][c0 + 2] = v.z;
        tile[r][c0 + 3] = v.w;
    }
    __syncthreads();
    int c = t >> 2;
    int rch = (t & 3) * 16;
    unsigned u0 = 0, u1 = 0;
    #pragma unroll
    for (int j = 0; j < 8; ++j) u0 |= q4(tile[rch + j][c], inv) << (4 * j);
    #pragma unroll
    for (int j = 0; j < 8; ++j) u1 |= q4(tile[rch + 8 + j][c], inv) << (4 * j);
    uint2 o; o.x = u0; o.y = u1;
    *(uint2*)&out[(size_t)(tc * 64 + c) * (R >> 1) + (size_t)(tr * 32) + (rch >> 1)] = o;
}

// ---------- fp4 MFMA helper ----------
__device__ __forceinline__ f32x4 mm16(i32x4 a, i32x4 b, f32x4 c) {
    i32x8 a8 = {a[0], a[1], a[2], a[3], 0, 0, 0, 0};
    i32x8 b8 = {b[0], b[1], b[2], b[3], 0, 0, 0, 0};
    return __builtin_amdgcn_mfma_scale_f32_16x16x128_f8f6f4(
        a8, b8, c, 4, 4, 0, 0x7f7f7f7f, 0, 0x7f7f7f7f);
}

// ====== g1: r2 structure — 128x128 block, BK=256, single-buffer (r13) =======
template <int RELU, int FUSE_AMAX>
__global__ __launch_bounds__(256, 2)
void gemm_fp4_g1(const unsigned char* __restrict__ Ap,
                 const unsigned char* __restrict__ Bp,
                 float* __restrict__ C, const float* __restrict__ bias,
                 const unsigned* __restrict__ amaxA,
                 const unsigned* __restrict__ amaxB,
                 unsigned* __restrict__ amaxOut,
                 int M, int N, int K) {
    __shared__ alignas(16) unsigned char As[128 * 128];
    __shared__ alignas(16) unsigned char Bs[128 * 128];
    __shared__ float smax[4];

    int nwg = gridDim.x, cpx = nwg >> 3;
    int wg = (blockIdx.x & 7) * cpx + (blockIdx.x >> 3);
    int MT = M >> 7;
    int tm = wg % MT, tn = wg / MT;

    int tid = threadIdx.x, lane = tid & 63, wid = tid >> 6;
    int wr = wid >> 1, wc = wid & 1;

    size_t Kb = (size_t)(K >> 1);

    int cs = ((lane & 7) ^ ((lane >> 3) & 7)) << 4;
    int srow = wid * 32 + (lane >> 3);
    const unsigned char* Abase = Ap + (size_t)(tm * 128 + srow) * Kb + cs;
    const unsigned char* Bbase = Bp + (size_t)(tn * 128 + srow) * Kb + cs;
    char* AsB = (char*)As;
    char* BsB = (char*)Bs;
    int ldsOff = wid * 4096;

    f32x4 acc[4][4] = {};
    int rrA = wr * 64 + (lane & 15);
    int rrB = wc * 64 + (lane & 15);

    int KT = K >> 8;
    for (int kt = 0; kt < KT; ++kt) {
        #pragma unroll
        for (int i = 0; i < 4; ++i) {
            __builtin_amdgcn_global_load_lds(
                (const AS1 void*)(Abase + (size_t)kt * 128 + (size_t)(i * 8) * Kb),
                (AS3 void*)(AsB + ldsOff + i * 1024), 16, 0, 0);
            __builtin_amdgcn_global_load_lds(
                (const AS1 void*)(Bbase + (size_t)kt * 128 + (size_t)(i * 8) * Kb),
                (AS3 void*)(BsB + ldsOff + i * 1024), 16, 0, 0);
        }
        __syncthreads();

        #pragma unroll
        for (int ks = 0; ks < 2; ++ks) {
            int slotOff = ((ks * 4 + (lane >> 4)) ^ (lane & 7)) << 4;
            i32x4 a[4], b[4];
            #pragma unroll
            for (int mi = 0; mi < 4; ++mi)
                a[mi] = *(const i32x4*)(AsB + (rrA + mi * 16) * 128 + slotOff);
            #pragma unroll
            for (int ni = 0; ni < 4; ++ni)
                b[ni] = *(const i32x4*)(BsB + (rrB + ni * 16) * 128 + slotOff);
            #pragma unroll
            for (int mi = 0; mi < 4; ++mi)
                #pragma unroll
                for (int ni = 0; ni < 4; ++ni)
                    acc[mi][ni] = mm16(a[mi], b[ni], acc[mi][ni]);
        }
        __syncthreads();
    }

    float s = scale_from_amax_bits(*amaxA) * scale_from_amax_bits(*amaxB);
    float vmax = 0.0f;
    int rowBase = tm * 128 + wr * 64 + (lane >> 4) * 4;
    int colBase = tn * 128 + wc * 64 + (lane & 15);
    #pragma unroll
    for (int mi = 0; mi < 4; ++mi) {
        #pragma unroll
        for (int ni = 0; ni < 4; ++ni) {
            int col = colBase + ni * 16;
            float bv = bias[col];
            int row = rowBase + mi * 16;
            #pragma unroll
            for (int r = 0; r < 4; ++r) {
                float v = acc[mi][ni][r] * s + bv;
                if (RELU) v = fmaxf(v, 0.0f);
                if (FUSE_AMAX) vmax = fmaxf(vmax, fabsf(v));
                __builtin_nontemporal_store(v, &C[(size_t)(row + r) * N + col]);
            }
        }
    }
    if (FUSE_AMAX) {
        #pragma unroll
        for (int off = 32; off > 0; off >>= 1)
            vmax = fmaxf(vmax, __shfl_xor(vmax, off));
        if (lane == 0) smax[wid] = vmax;
        __syncthreads();
        if (tid == 0) {
            vmax = fmaxf(fmaxf(smax[0], smax[1]), fmaxf(smax[2], smax[3]));
            atomicMax(amaxOut, __float_as_uint(vmax));
        }
    }
}

// ====== g2: 256x256 block, BK=128, 4-phase pipelined, 512 thr, 64KB LDS =====
// 8 waves (2M x 4N), wave tile 128x64: a[8] x b[4] = 32 MFMA / K-tile.
// Stage granularity: one gload_lds instr = 512 lanes x 16B = 128 rows x 64B;
// A tile = 2 instr (halves), B tile = 2 instr -> 4 loads/K-tile/wave.
// Pipeline 2 tiles deep: iter t computes tile t (buf d=t&1), stages tile t+2
// into buf d. vmcnt(4) at P4 retires tile t+1's loads (issued last iter).
// Stage-vs-read safety: B(buf d) reads retire at P1's lgkm0 (stage in P2);
// A reads retire at P2-end lgkm0 (stage in P3) — >=1 barrier separation.
__global__ __launch_bounds__(512, 2)
void gemm_fp4_g2p(const unsigned char* __restrict__ Ap,
                  const unsigned char* __restrict__ Bp,
                  float* __restrict__ C, const float* __restrict__ bias,
                  const unsigned* __restrict__ amaxA,
                  const unsigned* __restrict__ amaxB,
                  int M, int N, int K) {
    __shared__ alignas(16) unsigned char As[2][256 * 64];  // 32 KB
    __shared__ alignas(16) unsigned char Bs[2][256 * 64];  // 32 KB

    int nwg = gridDim.x, cpx = nwg >> 3;
    int wg = (blockIdx.x & 7) * cpx + (blockIdx.x >> 3);
    int MT = M >> 8;
    int tm = wg % MT, tn = wg / MT;

    int tid = threadIdx.x, lane = tid & 63, wid = tid >> 6;  // wid 0..7
    int wr = wid >> 2;          // 0..1 : 128-row half
    int wc = wid & 3;           // 0..3 : 64-col quarter

    size_t Kb = (size_t)(K >> 1);

    // staging: thread tid covers row tid>>2 (0..127), chunk tid&3; source
    // chunk pre-swizzled with the r8 involution slot = chunk ^ ((row>>1)&3).
    int csw = ((tid & 3) ^ ((tid >> 3) & 3)) << 4;
    int srow = tid >> 2;
    const unsigned char* Abase = Ap + (size_t)(tm * 256 + srow) * Kb + csw;
    const unsigned char* Bbase = Bp + (size_t)(tn * 256 + srow) * Kb + csw;
    char* AsB = (char*)As;
    char* BsB = (char*)Bs;
    int dstOff = wid << 10;     // + lane*16 by HW

#define STG_A2(d, kt, h)                                                      \
    __builtin_amdgcn_global_load_lds(                                         \
        (const AS1 void*)(Abase + (size_t)(kt) * 64 + (size_t)((h) * 128) * Kb), \
        (AS3 void*)(AsB + ((d) << 14) + ((h) << 13) + dstOff), 16, 0, 0)
#define STG_B2(d, kt, h)                                                      \
    __builtin_amdgcn_global_load_lds(                                         \
        (const AS1 void*)(Bbase + (size_t)(kt) * 64 + (size_t)((h) * 128) * Kb), \
        (AS3 void*)(BsB + ((d) << 14) + ((h) << 13) + dstOff), 16, 0, 0)

    f32x4 acc[8][4] = {};
    int l15 = lane & 15;
    int rrA = wr * 128 + l15;   // + mi*16
    int rrB = wc * 64 + l15;    // + ni*16
    int slotOff = (((lane >> 4) ^ ((lane >> 1) & 3)) << 4);

    int KT = K >> 7;            // 128 K-tiles of 128 fp4 (64B)

    // prologue: tile 0 -> buf0, tile 1 -> buf1; retire tile 0 (leave 4)
    STG_A2(0, 0, 0); STG_A2(0, 0, 1); STG_B2(0, 0, 0); STG_B2(0, 0, 1);
    STG_A2(1, 1, 0); STG_A2(1, 1, 1); STG_B2(1, 1, 0); STG_B2(1, 1, 1);
    asm volatile("s_waitcnt vmcnt(4)" ::: "memory");
    BAR;

    for (int t = 0; t < KT; ++t) {
        int d = t & 1;
        const char* Aq = AsB + (d << 14);
        const char* Bq = BsB + (d << 14);
        bool pf = (t + 2 < KT);
        i32x4 a0[4], a1[4], b[4];

        // ---- P1: read a[0..3] + b[0..3]; MFMA a0 x b01
        #pragma unroll
        for (int mi = 0; mi < 4; ++mi)
            a0[mi] = *(const i32x4*)(Aq + (rrA + mi * 16) * 64 + slotOff);
        #pragma unroll
        for (int ni = 0; ni < 4; ++ni)
            b[ni] = *(const i32x4*)(Bq + (rrB + ni * 16) * 64 + slotOff);
        SB0; BAR;
        LGKM0; SB0;
        __builtin_amdgcn_s_setprio(1);
        #pragma unroll
        for (int mi = 0; mi < 4; ++mi)
            #pragma unroll
            for (int ni = 0; ni < 2; ++ni)
                acc[mi][ni] = mm16(a0[mi], b[ni], acc[mi][ni]);
        __builtin_amdgcn_s_setprio(0);
        SB0; BAR;

        // ---- P2: read a[4..7]; stage B(t+2) into buf d (B reads retired P1)
        #pragma unroll
        for (int mi = 0; mi < 4; ++mi)
            a1[mi] = *(const i32x4*)(Aq + (rrA + (4 + mi) * 16) * 64 + slotOff);
        if (pf) { STG_B2(d, t + 2, 0); STG_B2(d, t + 2, 1); }
        SB0; BAR;
        __builtin_amdgcn_s_setprio(1);
        #pragma unroll
        for (int mi = 0; mi < 4; ++mi)
            #pragma unroll
            for (int ni = 2; ni < 4; ++ni)
                acc[mi][ni] = mm16(a0[mi], b[ni], acc[mi][ni]);
        __builtin_amdgcn_s_setprio(0);
        SB0;
        LGKM0;              // a1 retired before P2-end barrier
        BAR;

        // ---- P3: stage A(t+2) into buf d (A reads retired above); MFMA
        if (pf) { STG_A2(d, t + 2, 0); STG_A2(d, t + 2, 1); }
        SB0; BAR;
        __builtin_amdgcn_s_setprio(1);
        #pragma unroll
        for (int mi = 0; mi < 4; ++mi)
            #pragma unroll
            for (int ni = 0; ni < 2; ++ni)
                acc[4 + mi][ni] = mm16(a1[mi], b[ni], acc[4 + mi][ni]);
        __builtin_amdgcn_s_setprio(0);
        SB0; BAR;

        // ---- P4: MFMA; counted vmcnt gate (retire tile t+1's 4 loads)
        __builtin_amdgcn_s_setprio(1);
        #pragma unroll
        for (int mi = 0; mi < 4; ++mi)
            #pragma unroll
            for (int ni = 2; ni < 4; ++ni)
                acc[4 + mi][ni] = mm16(a1[mi], b[ni], acc[4 + mi][ni]);
        __builtin_amdgcn_s_setprio(0);
        SB0;
        if (pf) { asm volatile("s_waitcnt vmcnt(4)" ::: "memory"); }
        else    { asm volatile("s_waitcnt vmcnt(0)" ::: "memory"); }
        BAR;
    }
#undef STG_A2
#undef STG_B2

    float s = scale_from_amax_bits(*amaxA) * scale_from_amax_bits(*amaxB);
    int rowBase = tm * 256 + wr * 128 + (lane >> 4) * 4;
    int colBase = tn * 256 + wc * 64 + l15;
    #pragma unroll
    for (int mi = 0; mi < 8; ++mi) {
        #pragma unroll
        for (int ni = 0; ni < 4; ++ni) {
            int col = colBase + ni * 16;
            float bv = bias[col];
            int row = rowBase + mi * 16;
            #pragma unroll
            for (int r = 0; r < 4; ++r) {
                float v = acc[mi][ni][r] * s + bv;
                __builtin_nontemporal_store(v, &C[(size_t)(row + r) * N + col]);
            }
        }
    }
}

// ---------- launch ----------
extern "C" void kernel_launch(void* const* d_in, const int* in_sizes, int n_in,
                              void* d_out, int out_size, void* d_ws, size_t ws_size,
                              hipStream_t stream) {
    const float* x  = (const float*)d_in[0];
    const float* w1 = (const float*)d_in[1];
    const float* b1 = (const float*)d_in[2];
    const float* w2 = (const float*)d_in[3];
    const float* b2 = (const float*)d_in[4];
    float* out = (float*)d_out;

    const int B = 4096, DIN = 4096, DH = 16384, DOUT = 4096;

    const size_t off_amax = 0;                                    // 4 uints
    const size_t off_Xq   = 256;                                  // 8 MB
    const size_t off_W    = off_Xq + (size_t)B * DIN / 2;         // 32 MB
    const size_t off_h    = off_W + (size_t)DIN * DH / 2;         // 256 MB f32
    const size_t off_Hq   = off_h + (size_t)B * DH * 4;           // 32 MB
    const size_t needed   = off_Hq + (size_t)B * DH / 2;

    if (ws_size < needed) {
        sentinel_kernel<<<2048, 256, 0, stream>>>(out, (long long)out_size);
        return;
    }

    char* ws = (char*)d_ws;
    unsigned* amax = (unsigned*)(ws + off_amax);  // [0]=x [1]=w1 [2]=h [3]=w2
    unsigned char* Xq = (unsigned char*)(ws + off_Xq);
    unsigned char* Wq = (unsigned char*)(ws + off_W);
    float*         h  = (float*)(ws + off_h);
    unsigned char* Hq = (unsigned char*)(ws + off_Hq);

    zero4_kernel<<<1, 64, 0, stream>>>(amax);

    // --- w1: absmax then immediate reversed re-read (L3-adjacent) ---
    absmax_kernel<<<2048, 256, 0, stream>>>(w1, (long long)DIN * DH, amax + 1);
    quant_transpose_pack_kernel<<<(DIN / 64) * (DH / 64), 256, 0, stream>>>(
        w1, DIN, DH, amax + 1, Wq);

    // --- x: absmax then immediate quant ---
    absmax_kernel<<<2048, 256, 0, stream>>>(x, (long long)B * DIN, amax + 0);
    quant_pack_rev_kernel<<<2048, 256, 0, stream>>>(x, (long long)B * DIN,
                                                    amax + 0, (unsigned*)Xq);

    // h = relu(Q(x) @ Q(w1) + b1), fused absmax(h) -> amax[2]
    gemm_fp4_g1<1, 1><<<(B / 128) * (DH / 128), 256, 0, stream>>>(
        Xq, Wq, h, b1, amax + 0, amax + 1, amax + 2, B, DH, DIN);

    // --- h: quant immediately after GEMM1, reversed, NT loads ---
    quant_pack_rev_kernel<<<2048, 256, 0, stream>>>(h, (long long)B * DH,
                                                    amax + 2, (unsigned*)Hq);

    // --- w2: absmax then immediate reversed re-read ---
    absmax_kernel<<<2048, 256, 0, stream>>>(w2, (long long)DH * DOUT, amax + 3);
    quant_transpose_pack_kernel<<<(DH / 64) * (DOUT / 64), 256, 0, stream>>>(
        w2, DH, DOUT, amax + 3, Wq);

    // out = Q(h) @ Q(w2) + b2   [pipelined 256x256 kernel]
    gemm_fp4_g2p<<<(B / 256) * (DOUT / 256), 512, 0, stream>>>(
        Hq, Wq, out, b2, amax + 2, amax + 3, B, DOUT, DH);
}